// Round 1
// 420.820 us; speedup vs baseline: 1.0660x; 1.0660x over previous
//
#include <hip/hip_runtime.h>
#include <hip/hip_bf16.h>

#define BT   4096   // B*T
#define CD   1024   // C
#define TD   2048   // T
#define NH   16     // heads
#define DH   64     // head dim
#define BB   2      // batch

typedef __attribute__((ext_vector_type(8))) short bf16x8;
typedef __attribute__((ext_vector_type(4))) short bf16x4;
typedef __attribute__((ext_vector_type(4))) float f32x4;
typedef __attribute__((ext_vector_type(2))) unsigned int u32x2;

__device__ inline short f2bf(float f) {
    union { float fv; unsigned u; } x; x.fv = f;
    unsigned r = x.u + 0x7fffu + ((x.u >> 16) & 1u);
    return (short)(r >> 16);
}
__device__ inline float bf2f(short s) {
    union { unsigned u; float f; } x; x.u = ((unsigned)(unsigned short)s) << 16;
    return x.f;
}
__device__ inline unsigned pk2bf(float a, float b) {
    union { __hip_bfloat162 h; unsigned u; } cv;
    cv.h = __float22bfloat162_rn(float2{a, b});
    return cv.u;
}

// K=16 bf16 MFMA: A-frag layout (lane: m=l16, k=quad*4+j) is bit-identical to
// the 16x16 C-layout (m=quad*4+reg, n=l16) of the swapped S^T MFMA -> P stays
// in registers for PV (no LDS round-trip).
#if __has_builtin(__builtin_amdgcn_mfma_f32_16x16x16bf16_1k)
#define MFMA16x16(a, b, c) __builtin_amdgcn_mfma_f32_16x16x16bf16_1k(a, b, c, 0, 0, 0)
#elif __has_builtin(__builtin_amdgcn_mfma_f32_16x16x16_bf16)
#define MFMA16x16(a, b, c) __builtin_amdgcn_mfma_f32_16x16x16_bf16(a, b, c, 0, 0, 0)
#else
__device__ inline f32x4 mfma16_asm(bf16x4 a, bf16x4 b, f32x4 c) {
    f32x4 d;
    asm volatile("v_mfma_f32_16x16x16_bf16 %0, %1, %2, %3"
                 : "=v"(d) : "v"(a), "v"(b), "v"(c));
    return d;
}
#define MFMA16x16(a, b, c) mfma16_asm(a, b, c)
#endif

__device__ inline void gload_lds16(const short* g, short* lds) {
    __builtin_amdgcn_global_load_lds(
        (const __attribute__((address_space(1))) void*)g,
        (__attribute__((address_space(3))) void*)lds, 16, 0, 0);
}

// ---------------- LayerNorm: one block per row (C=1024), fp32 in, bf16 out ----
__launch_bounds__(256)
__global__ void ln_kernel(const float* __restrict__ x,
                          const float* __restrict__ g,
                          const float* __restrict__ be,
                          short* __restrict__ out) {
    __shared__ float red[2][4];
    const int row = blockIdx.x;
    const float* xr = x + (size_t)row * CD;
    float s = 0.f, ss = 0.f;
    for (int c = threadIdx.x; c < CD; c += 256) {
        float v = xr[c];
        s += v; ss += v * v;
    }
    #pragma unroll
    for (int off = 32; off > 0; off >>= 1) {
        s  += __shfl_down(s,  off, 64);
        ss += __shfl_down(ss, off, 64);
    }
    int wid = threadIdx.x >> 6, lane = threadIdx.x & 63;
    if (lane == 0) { red[0][wid] = s; red[1][wid] = ss; }
    __syncthreads();
    float sum   = red[0][0] + red[0][1] + red[0][2] + red[0][3];
    float sumsq = red[1][0] + red[1][1] + red[1][2] + red[1][3];
    float mu   = sum * (1.f / CD);
    float var  = sumsq * (1.f / CD) - mu * mu;
    float rstd = rsqrtf(var + 1e-5f);
    short* orow = out + (size_t)row * CD;
    for (int c = threadIdx.x; c < CD; c += 256) {
        float v = xr[c];
        orow[c] = f2bf((v - mu) * rstd * g[c] + be[c]);
    }
}

// ------------- Fused weight prep: all 64x64 fp32->bf16 transpose tiles -------
// blocks 0..767: Wq/Wk/Wv (per-head CDxDH slices) -> wqt (3,H,DH,C)
// 768..1023: Wo (CDxCD); 1024..2047: W1 (CDx4CD); 2048..3071: W2 (4CDxCD)
__launch_bounds__(256)
__global__ void prep_weights(const float* __restrict__ Wq, const float* __restrict__ Wk,
                             const float* __restrict__ Wv, const float* __restrict__ Wo,
                             const float* __restrict__ W1, const float* __restrict__ W2,
                             short* __restrict__ wqt, short* __restrict__ wot,
                             short* __restrict__ w1t, short* __restrict__ w2t) {
    __shared__ float tt[64][65];
    const int id = blockIdx.x;
    const float* in; short* out; int R, Cc, r0, c0;
    if (id < 768) {
        int which = id >> 8, rem = id & 255, hh = rem >> 4, ry = rem & 15;
        in  = (which == 0 ? Wq : which == 1 ? Wk : Wv) + (size_t)hh * CD * DH;
        out = wqt + (size_t)which * CD * CD + (size_t)hh * DH * CD;
        R = CD; Cc = DH; r0 = ry * 64; c0 = 0;
    } else if (id < 1024) {
        int t = id - 768;  in = Wo; out = wot; R = CD;     Cc = CD;     r0 = (t >> 4) * 64; c0 = (t & 15) * 64;
    } else if (id < 2048) {
        int t = id - 1024; in = W1; out = w1t; R = CD;     Cc = 4 * CD; r0 = (t >> 6) * 64; c0 = (t & 63) * 64;
    } else {
        int t = id - 2048; in = W2; out = w2t; R = 4 * CD; Cc = CD;     r0 = (t >> 4) * 64; c0 = (t & 15) * 64;
    }
    const int tid = threadIdx.x;
    #pragma unroll
    for (int i = 0; i < 16; ++i) {
        int e = i * 256 + tid;
        tt[e >> 6][e & 63] = in[(size_t)(r0 + (e >> 6)) * Cc + c0 + (e & 63)];
    }
    __syncthreads();
    #pragma unroll
    for (int i = 0; i < 16; ++i) {
        int e = i * 256 + tid;
        out[(size_t)(c0 + (e >> 6)) * R + r0 + (e & 63)] = f2bf(tt[e & 63][e >> 6]);
    }
}

// ------------- V transpose: vbf (BT x C bf16) -> vtg[b][h][d][t] bf16 -------
__launch_bounds__(256)
__global__ void vtrans(const short* __restrict__ vin, short* __restrict__ vout) {
    __shared__ short t[64 * 65];
    const int tid = threadIdx.x;
    const int bh = blockIdx.y;
    const int t0 = blockIdx.x * 64;
    const int b = bh >> 4, h = bh & 15;
    const short* src = vin + (size_t)b * TD * CD + (size_t)h * DH;
    short* dst = vout + (size_t)bh * DH * TD;
    #pragma unroll
    for (int i = 0; i < 16; ++i) {
        int e = i * 256 + tid;
        t[(e >> 6) * 65 + (e & 63)] = src[(size_t)(t0 + (e >> 6)) * CD + (e & 63)];
    }
    __syncthreads();
    #pragma unroll
    for (int i = 0; i < 16; ++i) {
        int e = i * 256 + tid;
        int d = e >> 6, tt = e & 63;
        dst[(size_t)d * TD + t0 + tt] = t[tt * 65 + d];
    }
}

// ---------------- MFMA GEMM: C(128 x TN) = A(M x K) . Bt(N x K)^T, bf16 ------
// MODE 1: + bias + fp32 resid -> fp32 out
// MODE 2: + bias, relu -> bf16 out
// MODE 5: QKV merged: N=3072; seg=col>>10 -> outb + seg*BT*CD; seg0 scaled by
//         C^-0.5 * log2(e)  (attention uses exp2)
template <int MODE, int TN>
__launch_bounds__(256)
__global__ void gemm_mfma(const short* __restrict__ A,
                          const short* __restrict__ Bt,
                          const float* __restrict__ bias,
                          const float* __restrict__ resid,
                          float* __restrict__ outf,
                          short* __restrict__ outb,
                          int N, int K) {
    __shared__ short As[128 * 32];
    __shared__ short Bs[TN * 32];
    const int tid = threadIdx.x;
    const int w = tid >> 6, lane = tid & 63;
    const int quad = lane >> 4, l16 = lane & 15;
    const int wr = w >> 1, wc = w & 1;
    const int m0 = blockIdx.y * 128, n0 = blockIdx.x * TN;
    const int NT = TN / 32;

    f32x4 acc[4][NT] = {};

    for (int k0 = 0; k0 < K; k0 += 32) {
        __syncthreads();
        #pragma unroll
        for (int i = 0; i < 2; ++i) {
            int chunk = i * 256 + tid;
            int row = chunk >> 2, kc = chunk & 3;
            gload_lds16(A + (size_t)(m0 + row) * K + k0 + kc * 8,
                        &As[(i * 256 + w * 64) * 8]);
        }
        #pragma unroll
        for (int i = 0; i < TN / 64; ++i) {
            int chunk = i * 256 + tid;
            int row = chunk >> 2, kc = chunk & 3;
            gload_lds16(Bt + (size_t)(n0 + row) * K + k0 + kc * 8,
                        &Bs[(i * 256 + w * 64) * 8]);
        }
        __syncthreads();

        bf16x8 a[4], b[NT];
        #pragma unroll
        for (int mt = 0; mt < 4; ++mt)
            a[mt] = *(const bf16x8*)&As[(wr * 64 + mt * 16 + l16) * 32 + quad * 8];
        #pragma unroll
        for (int nt = 0; nt < NT; ++nt)
            b[nt] = *(const bf16x8*)&Bs[(wc * (TN / 2) + nt * 16 + l16) * 32 + quad * 8];
        #pragma unroll
        for (int mt = 0; mt < 4; ++mt)
            #pragma unroll
            for (int nt = 0; nt < NT; ++nt)
                acc[mt][nt] = __builtin_amdgcn_mfma_f32_16x16x32_bf16(a[mt], b[nt], acc[mt][nt], 0, 0, 0);
    }

    const float qsc = (MODE == 5 && n0 < CD) ? 0.03125f * 1.44269504f : 1.0f;
    short* ob5 = (MODE == 5) ? outb + (size_t)(n0 >> 10) * BT * CD : nullptr;

    #pragma unroll
    for (int mt = 0; mt < 4; ++mt)
        #pragma unroll
        for (int nt = 0; nt < NT; ++nt)
            #pragma unroll
            for (int reg = 0; reg < 4; ++reg) {
                int row = m0 + wr * 64 + mt * 16 + quad * 4 + reg;
                int col = n0 + wc * (TN / 2) + nt * 16 + l16;
                float v = acc[mt][nt][reg];
                if (MODE == 1) { v += bias[col] + resid[(size_t)row * N + col];
                                 outf[(size_t)row * N + col] = v; }
                if (MODE == 2) { v = fmaxf(v + bias[col], 0.f);
                                 outb[(size_t)row * N + col] = f2bf(v); }
                if (MODE == 5) { ob5[(size_t)row * CD + (col & 1023)] = f2bf(v * qsc); }
            }
}

// ---------------- Flash attention, split-K, MFMA bf16, no-max softmax --------
// R10 changes vs R9:
//  * PV uses K=16 MFMA (mfma_f32_16x16x16_bf16): its A-fragment layout
//    (lane: m=l16, k=quad*4+j) is bit-identical to the S^T C-layout
//    (m=quad*4+reg, n=l16), so exp2'd P feeds PV directly from registers.
//    The Pl LDS buffer (19.5 KB, half the block's LDS) and its
//    8 ds_write_b64 + 4 ds_read_b128 per tile/wave are gone.
//  * Freed LDS spent on double-buffered K/V with single-barrier prefetch:
//    issue next-tile global loads -> compute current -> ds_write next ->
//    one __syncthreads per tile (was 2). HBM latency hides under compute.
//  * V B-frag is a ds_read_b64 at ct*16+quad*4 (STR=76 keeps it 2-way max,
//    i.e. conflict-free on 32 banks).
#define BQ   128
#define BK   64
#define STR  76

__launch_bounds__(256)
__global__ void attn_mfma(const short* __restrict__ q,
                          const short* __restrict__ k,
                          const short* __restrict__ vt,
                          short* __restrict__ opart,
                          float* __restrict__ lpart) {
    __shared__ short Ks[2][BK * STR];
    __shared__ short Vt[2][DH * STR];

    const int tid  = threadIdx.x;
    const int w = tid >> 6, lane = tid & 63;
    const int quad = lane >> 4, l16 = lane & 15;
    const int h = blockIdx.y;
    const int b = blockIdx.z >> 1, split = blockIdx.z & 1;
    const int q0 = blockIdx.x * BQ;
    const size_t base  = (size_t)b * TD * CD + (size_t)h * DH;
    const size_t vbase = (size_t)(b * NH + h) * DH * TD;

    // Q frags (N-side of S^T mfma): lane holds Q[q=l16][d=quad*8+j]
    bf16x8 qf[2][2];
    #pragma unroll
    for (int rt = 0; rt < 2; ++rt) {
        const short* qp = q + base + (size_t)(q0 + w * 32 + rt * 16 + l16) * CD;
        qf[rt][0] = *(const bf16x8*)&qp[quad * 8];
        qf[rt][1] = *(const bf16x8*)&qp[32 + quad * 8];
    }

    float l_p[2] = {};   // per-lane: q = q0+w*32+rt*16+l16, keys quad*4+reg
    f32x4 O[2][4] = {};

    const int kbeg = split * (TD / 2);
    const int NTI = (TD / 2) / BK;

    // prologue: stage tile 0 into buffer 0
    #pragma unroll
    for (int i = 0; i < 2; ++i) {
        int chunk = i * 256 + tid;
        int r8 = chunk >> 3, c8 = (chunk & 7) * 8;
        *(bf16x8*)&Ks[0][r8 * STR + c8] =
            *(const bf16x8*)&k[base + (size_t)(kbeg + r8) * CD + c8];
        *(bf16x8*)&Vt[0][r8 * STR + c8] =
            *(const bf16x8*)&vt[vbase + (size_t)r8 * TD + kbeg + c8];
    }
    __syncthreads();

    int cur = 0;
    for (int it = 0; it < NTI; ++it) {
        // issue next-tile prefetch loads (consumed after compute)
        bf16x8 kr[2], vr[2];
        const int ktn = kbeg + (it + 1) * BK;
        if (it + 1 < NTI) {
            #pragma unroll
            for (int i = 0; i < 2; ++i) {
                int chunk = i * 256 + tid;
                int r8 = chunk >> 3, c8 = (chunk & 7) * 8;
                kr[i] = *(const bf16x8*)&k[base + (size_t)(ktn + r8) * CD + c8];
                vr[i] = *(const bf16x8*)&vt[vbase + (size_t)r8 * TD + ktn + c8];
            }
        }

        const short* Kc = Ks[cur];
        const short* Vc = Vt[cur];

        // per 16-key group: S^T = K.Q^T -> exp2 -> pa (PV A-frag, in regs) -> PV
        #pragma unroll
        for (int ct = 0; ct < 4; ++ct) {
            bf16x8 kb0 = *(const bf16x8*)&Kc[(ct * 16 + l16) * STR + quad * 8];
            bf16x8 kb1 = *(const bf16x8*)&Kc[(ct * 16 + l16) * STR + 32 + quad * 8];
            bf16x4 pa[2];
            #pragma unroll
            for (int rt = 0; rt < 2; ++rt) {
                f32x4 acc = (f32x4){0.f, 0.f, 0.f, 0.f};
                acc = __builtin_amdgcn_mfma_f32_16x16x32_bf16(kb0, qf[rt][0], acc, 0, 0, 0);
                acc = __builtin_amdgcn_mfma_f32_16x16x32_bf16(kb1, qf[rt][1], acc, 0, 0, 0);
                float p0 = exp2f(acc[0]), p1 = exp2f(acc[1]);
                float p2 = exp2f(acc[2]), p3 = exp2f(acc[3]);
                l_p[rt] += (p0 + p1) + (p2 + p3);
                union { u32x2 u; bf16x4 s; } cv;
                cv.u = (u32x2){pk2bf(p0, p1), pk2bf(p2, p3)};
                pa[rt] = cv.s;
            }
            #pragma unroll
            for (int dt = 0; dt < 4; ++dt) {
                bf16x4 vb = *(const bf16x4*)&Vc[(dt * 16 + l16) * STR + ct * 16 + quad * 4];
                #pragma unroll
                for (int rt = 0; rt < 2; ++rt)
                    O[rt][dt] = MFMA16x16(pa[rt], vb, O[rt][dt]);
            }
        }

        // write prefetched tile into the other buffer, single barrier
        if (it + 1 < NTI) {
            #pragma unroll
            for (int i = 0; i < 2; ++i) {
                int chunk = i * 256 + tid;
                int r8 = chunk >> 3, c8 = (chunk & 7) * 8;
                *(bf16x8*)&Ks[cur ^ 1][r8 * STR + c8] = kr[i];
                *(bf16x8*)&Vt[cur ^ 1][r8 * STR + c8] = vr[i];
            }
        }
        __syncthreads();
        cur ^= 1;
    }

    // epilogue: unnormalized O (bf16) + l (fp32) per split
    short* osp = opart + (size_t)split * BT * CD;
    float* lsp = lpart + (size_t)split * BB * NH * TD + (size_t)(b * NH + h) * TD;
    #pragma unroll
    for (int rt = 0; rt < 2; ++rt) {
        float l = l_p[rt];
        l += __shfl_xor(l, 16, 64);
        l += __shfl_xor(l, 32, 64);
        if (lane < 16) lsp[q0 + w * 32 + rt * 16 + lane] = l;
        #pragma unroll
        for (int reg = 0; reg < 4; ++reg) {
            int row = q0 + w * 32 + rt * 16 + quad * 4 + reg;
            short* op = osp + base + (size_t)row * CD;
            #pragma unroll
            for (int dt = 0; dt < 4; ++dt)
                op[dt * 16 + l16] = f2bf(O[rt][dt][reg]);
        }
    }
}

// ---------------- Combine split-K partials: ob = (O0+O1)/(l0+l1), bf16 -------
__launch_bounds__(256)
__global__ void attn_combine(const short* __restrict__ opart,
                             const float* __restrict__ lpart,
                             short* __restrict__ ob) {
    const size_t idx = ((size_t)blockIdx.x * 256 + threadIdx.x) * 8;
    const int row = (int)(idx >> 10);        // / CD
    const int col = (int)(idx & 1023);
    const int b = row >> 11, qq = row & (TD - 1), hh = col >> 6;
    const size_t lbase = (size_t)(b * NH + hh) * TD + qq;
    const float l0 = lpart[lbase];
    const float l1 = lpart[(size_t)BB * NH * TD + lbase];
    const float inv = 1.f / (l0 + l1);
    bf16x8 a = *(const bf16x8*)&opart[idx];
    bf16x8 c = *(const bf16x8*)&opart[(size_t)BT * CD + idx];
    bf16x8 r;
    #pragma unroll
    for (int j = 0; j < 8; ++j)
        r[j] = f2bf((bf2f(a[j]) + bf2f(c[j])) * inv);
    *(bf16x8*)&ob[idx] = r;
}

extern "C" void kernel_launch(void* const* d_in, const int* in_sizes, int n_in,
                              void* d_out, int out_size, void* d_ws, size_t ws_size,
                              hipStream_t stream) {
    const float* x   = (const float*)d_in[0];
    const float* Wq  = (const float*)d_in[1];
    const float* Wk  = (const float*)d_in[2];
    const float* Wv  = (const float*)d_in[3];
    const float* Wo  = (const float*)d_in[4];
    const float* bo  = (const float*)d_in[5];
    const float* W1  = (const float*)d_in[6];
    const float* b1  = (const float*)d_in[7];
    const float* W2  = (const float*)d_in[8];
    const float* b2  = (const float*)d_in[9];
    const float* g1  = (const float*)d_in[10];
    const float* be1 = (const float*)d_in[11];
    const float* g2  = (const float*)d_in[12];
    const float* be2 = (const float*)d_in[13];
    float* out = (float*)d_out;

    const size_t SZ = (size_t)BT * CD;  // 4M elements
    float* ws  = (float*)d_ws;
    short* qbf = (short*)ws;                       // [0,1.5SZ): q|k|v bf16
    short* kbf = qbf + SZ;
    short* vbf = qbf + 2 * SZ;
    float* lpart = ws + SZ + SZ / 2;               // [1.5SZ,+128K floats)
    short* opart = (short*)(ws + 2 * SZ);          // [2SZ,3SZ): 2 x SZ bf16
    float* x1  = ws + 2 * SZ;                      // [2SZ,3SZ): after combine
    short* h   = (short*)(ws + 3 * SZ);            // [3SZ,3.5SZ)
    short* ob  = (short*)(ws + 3 * SZ + SZ / 2);   // [3.5SZ,4SZ)
    short* wqt = (short*)(ws + 4 * SZ);            // [4SZ,4.5SZ): 3xCD*CD + CD*CD
    short* wot = wqt + 3 * CD * CD;
    short* w1t = (short*)(ws + 4 * SZ + SZ / 2);   // [4.5SZ,5SZ)
    short* w2t = (short*)(ws + 5 * SZ);            // [5SZ,5.5SZ)
    short* vtg = (short*)(ws + 5 * SZ + SZ / 2);   // [5.5SZ,6SZ): V^T global
    short* ff1 = (short*)ws;                       // [0,2SZ): reuses dead q/k/v

    // 1) h1 = LN(x)  (bf16)
    ln_kernel<<<BT, 256, 0, stream>>>(x, g1, be1, h);

    // 2) all weight transposes fused (bf16 B^T layouts)
    prep_weights<<<3072, 256, 0, stream>>>(Wq, Wk, Wv, Wo, W1, W2, wqt, wot, w1t, w2t);

    // 3) merged q|k|v = h1 @ [Wq|Wk|Wv]  (bf16; C^-0.5*log2e folded into q)
    gemm_mfma<5, 128><<<dim3(24, 32), 256, 0, stream>>>(h, wqt, nullptr, nullptr, nullptr, qbf, 3 * CD, CD);

    // 4) vtg = V^T per (b,h)
    vtrans<<<dim3(TD / 64, 2 * NH), 256, 0, stream>>>(vbf, vtg);

    // 5) attention split-K -> opart, lpart
    attn_mfma<<<dim3(TD / BQ, NH, BB * 2), 256, 0, stream>>>(qbf, kbf, vtg, opart, lpart);

    // 6) combine -> ob (bf16, concat-head layout)
    attn_combine<<<dim3((int)(SZ / (256 * 8))), 256, 0, stream>>>(opart, lpart, ob);

    // 7) x1 = ob @ Wo + bo + x  (fp32; overwrites opart region after combine)
    gemm_mfma<1, 64><<<dim3(16, 32), 256, 0, stream>>>(ob, wot, bo, x, x1, nullptr, CD, CD);

    // 8) h2 = LN(x1)  (bf16)
    ln_kernel<<<BT, 256, 0, stream>>>(x1, g2, be2, h);

    // 9) ff1 = relu(h2 @ W1 + b1)  (bf16, N=4096)
    gemm_mfma<2, 128><<<dim3(32, 32), 256, 0, stream>>>(h, w1t, b1, nullptr, nullptr, ff1, 4 * CD, CD);

    // 10) out = ff1 @ W2 + b2 + x1  (fp32, K=4096)
    gemm_mfma<1, 64><<<dim3(16, 32), 256, 0, stream>>>(ff1, w2t, b2, x1, out, nullptr, CD, 4 * CD);
}

// Round 2
// 415.638 us; speedup vs baseline: 1.0793x; 1.0125x over previous
//
#include <hip/hip_runtime.h>
#include <hip/hip_bf16.h>

#define BT   4096   // B*T
#define CD   1024   // C
#define TD   2048   // T
#define NH   16     // heads
#define DH   64     // head dim
#define BB   2      // batch

typedef __attribute__((ext_vector_type(8))) short bf16x8;
typedef __attribute__((ext_vector_type(4))) short bf16x4;
typedef __attribute__((ext_vector_type(4))) float f32x4;
typedef __attribute__((ext_vector_type(2))) unsigned int u32x2;

__device__ inline short f2bf(float f) {
    union { float fv; unsigned u; } x; x.fv = f;
    unsigned r = x.u + 0x7fffu + ((x.u >> 16) & 1u);
    return (short)(r >> 16);
}
__device__ inline float bf2f(short s) {
    union { unsigned u; float f; } x; x.u = ((unsigned)(unsigned short)s) << 16;
    return x.f;
}
__device__ inline unsigned pk2bf(float a, float b) {
    union { __hip_bfloat162 h; unsigned u; } cv;
    cv.h = __float22bfloat162_rn(float2{a, b});
    return cv.u;
}

// raw v_exp_f32 (2^x): avoid any OCML guard sequence
#if __has_builtin(__builtin_amdgcn_exp2f)
#define EXP2(x) __builtin_amdgcn_exp2f(x)
#else
#define EXP2(x) exp2f(x)
#endif

// K=16 bf16 MFMA: A-frag layout (lane: m=l16, k=quad*4+j) is bit-identical to
// the 16x16 C-layout (m=quad*4+reg, n=l16) of the swapped S^T MFMA -> P stays
// in registers for PV (no LDS round-trip).
#if __has_builtin(__builtin_amdgcn_mfma_f32_16x16x16bf16_1k)
#define MFMA16x16(a, b, c) __builtin_amdgcn_mfma_f32_16x16x16bf16_1k(a, b, c, 0, 0, 0)
#elif __has_builtin(__builtin_amdgcn_mfma_f32_16x16x16_bf16)
#define MFMA16x16(a, b, c) __builtin_amdgcn_mfma_f32_16x16x16_bf16(a, b, c, 0, 0, 0)
#else
__device__ inline f32x4 mfma16_asm(bf16x4 a, bf16x4 b, f32x4 c) {
    f32x4 d;
    asm volatile("v_mfma_f32_16x16x16_bf16 %0, %1, %2, %3"
                 : "=v"(d) : "v"(a), "v"(b), "v"(c));
    return d;
}
#define MFMA16x16(a, b, c) mfma16_asm(a, b, c)
#endif

__device__ inline void gload_lds16(const short* g, short* lds) {
    __builtin_amdgcn_global_load_lds(
        (const __attribute__((address_space(1))) void*)g,
        (__attribute__((address_space(3))) void*)lds, 16, 0, 0);
}

// ---------------- LayerNorm: one block per row (C=1024), fp32 in, bf16 out ----
__launch_bounds__(256)
__global__ void ln_kernel(const float* __restrict__ x,
                          const float* __restrict__ g,
                          const float* __restrict__ be,
                          short* __restrict__ out) {
    __shared__ float red[2][4];
    const int row = blockIdx.x;
    const float* xr = x + (size_t)row * CD;
    float s = 0.f, ss = 0.f;
    for (int c = threadIdx.x; c < CD; c += 256) {
        float v = xr[c];
        s += v; ss += v * v;
    }
    #pragma unroll
    for (int off = 32; off > 0; off >>= 1) {
        s  += __shfl_down(s,  off, 64);
        ss += __shfl_down(ss, off, 64);
    }
    int wid = threadIdx.x >> 6, lane = threadIdx.x & 63;
    if (lane == 0) { red[0][wid] = s; red[1][wid] = ss; }
    __syncthreads();
    float sum   = red[0][0] + red[0][1] + red[0][2] + red[0][3];
    float sumsq = red[1][0] + red[1][1] + red[1][2] + red[1][3];
    float mu   = sum * (1.f / CD);
    float var  = sumsq * (1.f / CD) - mu * mu;
    float rstd = rsqrtf(var + 1e-5f);
    short* orow = out + (size_t)row * CD;
    for (int c = threadIdx.x; c < CD; c += 256) {
        float v = xr[c];
        orow[c] = f2bf((v - mu) * rstd * g[c] + be[c]);
    }
}

// ------------- Fused weight prep: all 64x64 fp32->bf16 transpose tiles -------
// blocks 0..767: Wq/Wk/Wv (per-head CDxDH slices) -> wqt (3,H,DH,C)
// 768..1023: Wo (CDxCD); 1024..2047: W1 (CDx4CD); 2048..3071: W2 (4CDxCD)
__launch_bounds__(256)
__global__ void prep_weights(const float* __restrict__ Wq, const float* __restrict__ Wk,
                             const float* __restrict__ Wv, const float* __restrict__ Wo,
                             const float* __restrict__ W1, const float* __restrict__ W2,
                             short* __restrict__ wqt, short* __restrict__ wot,
                             short* __restrict__ w1t, short* __restrict__ w2t) {
    __shared__ float tt[64][65];
    const int id = blockIdx.x;
    const float* in; short* out; int R, Cc, r0, c0;
    if (id < 768) {
        int which = id >> 8, rem = id & 255, hh = rem >> 4, ry = rem & 15;
        in  = (which == 0 ? Wq : which == 1 ? Wk : Wv) + (size_t)hh * CD * DH;
        out = wqt + (size_t)which * CD * CD + (size_t)hh * DH * CD;
        R = CD; Cc = DH; r0 = ry * 64; c0 = 0;
    } else if (id < 1024) {
        int t = id - 768;  in = Wo; out = wot; R = CD;     Cc = CD;     r0 = (t >> 4) * 64; c0 = (t & 15) * 64;
    } else if (id < 2048) {
        int t = id - 1024; in = W1; out = w1t; R = CD;     Cc = 4 * CD; r0 = (t >> 6) * 64; c0 = (t & 63) * 64;
    } else {
        int t = id - 2048; in = W2; out = w2t; R = 4 * CD; Cc = CD;     r0 = (t >> 4) * 64; c0 = (t & 15) * 64;
    }
    const int tid = threadIdx.x;
    #pragma unroll
    for (int i = 0; i < 16; ++i) {
        int e = i * 256 + tid;
        tt[e >> 6][e & 63] = in[(size_t)(r0 + (e >> 6)) * Cc + c0 + (e & 63)];
    }
    __syncthreads();
    #pragma unroll
    for (int i = 0; i < 16; ++i) {
        int e = i * 256 + tid;
        out[(size_t)(c0 + (e >> 6)) * R + r0 + (e & 63)] = f2bf(tt[e & 63][e >> 6]);
    }
}

// ------------- V transpose: vbf (BT x C bf16) -> vtg[b][h][d][t] bf16 -------
__launch_bounds__(256)
__global__ void vtrans(const short* __restrict__ vin, short* __restrict__ vout) {
    __shared__ short t[64 * 65];
    const int tid = threadIdx.x;
    const int bh = blockIdx.y;
    const int t0 = blockIdx.x * 64;
    const int b = bh >> 4, h = bh & 15;
    const short* src = vin + (size_t)b * TD * CD + (size_t)h * DH;
    short* dst = vout + (size_t)bh * DH * TD;
    #pragma unroll
    for (int i = 0; i < 16; ++i) {
        int e = i * 256 + tid;
        t[(e >> 6) * 65 + (e & 63)] = src[(size_t)(t0 + (e >> 6)) * CD + (e & 63)];
    }
    __syncthreads();
    #pragma unroll
    for (int i = 0; i < 16; ++i) {
        int e = i * 256 + tid;
        int d = e >> 6, tt = e & 63;
        dst[(size_t)d * TD + t0 + tt] = t[tt * 65 + d];
    }
}

// ---------------- MFMA GEMM: C(128 x TN) = A(M x K) . Bt(N x K)^T, bf16 ------
// MODE 1: + bias + fp32 resid -> fp32 out
// MODE 2: + bias, relu -> bf16 out
// MODE 5: QKV merged: N=3072; seg=col>>10 -> outb + seg*BT*CD; seg0 scaled by
//         C^-0.5 * log2(e)  (attention uses exp2)
template <int MODE, int TN>
__launch_bounds__(256)
__global__ void gemm_mfma(const short* __restrict__ A,
                          const short* __restrict__ Bt,
                          const float* __restrict__ bias,
                          const float* __restrict__ resid,
                          float* __restrict__ outf,
                          short* __restrict__ outb,
                          int N, int K) {
    __shared__ short As[128 * 32];
    __shared__ short Bs[TN * 32];
    const int tid = threadIdx.x;
    const int w = tid >> 6, lane = tid & 63;
    const int quad = lane >> 4, l16 = lane & 15;
    const int wr = w >> 1, wc = w & 1;
    const int m0 = blockIdx.y * 128, n0 = blockIdx.x * TN;
    const int NT = TN / 32;

    f32x4 acc[4][NT] = {};

    for (int k0 = 0; k0 < K; k0 += 32) {
        __syncthreads();
        #pragma unroll
        for (int i = 0; i < 2; ++i) {
            int chunk = i * 256 + tid;
            int row = chunk >> 2, kc = chunk & 3;
            gload_lds16(A + (size_t)(m0 + row) * K + k0 + kc * 8,
                        &As[(i * 256 + w * 64) * 8]);
        }
        #pragma unroll
        for (int i = 0; i < TN / 64; ++i) {
            int chunk = i * 256 + tid;
            int row = chunk >> 2, kc = chunk & 3;
            gload_lds16(Bt + (size_t)(n0 + row) * K + k0 + kc * 8,
                        &Bs[(i * 256 + w * 64) * 8]);
        }
        __syncthreads();

        bf16x8 a[4], b[NT];
        #pragma unroll
        for (int mt = 0; mt < 4; ++mt)
            a[mt] = *(const bf16x8*)&As[(wr * 64 + mt * 16 + l16) * 32 + quad * 8];
        #pragma unroll
        for (int nt = 0; nt < NT; ++nt)
            b[nt] = *(const bf16x8*)&Bs[(wc * (TN / 2) + nt * 16 + l16) * 32 + quad * 8];
        #pragma unroll
        for (int mt = 0; mt < 4; ++mt)
            #pragma unroll
            for (int nt = 0; nt < NT; ++nt)
                acc[mt][nt] = __builtin_amdgcn_mfma_f32_16x16x32_bf16(a[mt], b[nt], acc[mt][nt], 0, 0, 0);
    }

    const float qsc = (MODE == 5 && n0 < CD) ? 0.03125f * 1.44269504f : 1.0f;
    short* ob5 = (MODE == 5) ? outb + (size_t)(n0 >> 10) * BT * CD : nullptr;

    #pragma unroll
    for (int mt = 0; mt < 4; ++mt)
        #pragma unroll
        for (int nt = 0; nt < NT; ++nt)
            #pragma unroll
            for (int reg = 0; reg < 4; ++reg) {
                int row = m0 + wr * 64 + mt * 16 + quad * 4 + reg;
                int col = n0 + wc * (TN / 2) + nt * 16 + l16;
                float v = acc[mt][nt][reg];
                if (MODE == 1) { v += bias[col] + resid[(size_t)row * N + col];
                                 outf[(size_t)row * N + col] = v; }
                if (MODE == 2) { v = fmaxf(v + bias[col], 0.f);
                                 outb[(size_t)row * N + col] = f2bf(v); }
                if (MODE == 5) { ob5[(size_t)row * CD + (col & 1023)] = f2bf(v * qsc); }
            }
}

// ---------------- Flash attention, split-K, MFMA bf16, no-max softmax --------
// R11 changes vs R10:
//  * 2-tile-deep register prefetch: loads for tile t+2 issue during tile t;
//    tile t+1's regs are ds_written after tile t's compute. Compiler derives
//    counted vmcnt(4) (4 younger loads in flight) instead of a drain -> load
//    window ~1.7 tile phases, covers HBM latency. Loop hand-unrolled x2 with
//    named reg sets A/B (no runtime-indexed reg arrays).
//  * STR 76 -> 68: still conflict-free for all access patterns (b128 K-reads
//    8 slots/bank = minimum; b64 V-reads 4/bank; staging writes 8/bank) and
//    LDS drops 38912 -> 34816 B: 4 blocks/CU with 21KB slack.
//  * setprio(1) around the MFMA/exp2 compute cluster (T5, attn +4-7%).
//  * raw v_exp_f32 via __builtin_amdgcn_exp2f.
#define BQ   128
#define BK   64
#define STR  68

__launch_bounds__(256)
__global__ void attn_mfma(const short* __restrict__ q,
                          const short* __restrict__ k,
                          const short* __restrict__ vt,
                          short* __restrict__ opart,
                          float* __restrict__ lpart) {
    __shared__ short Ks[2][BK * STR];
    __shared__ short Vt[2][DH * STR];

    const int tid  = threadIdx.x;
    const int w = tid >> 6, lane = tid & 63;
    const int quad = lane >> 4, l16 = lane & 15;
    const int h = blockIdx.y;
    const int b = blockIdx.z >> 1, split = blockIdx.z & 1;
    const int q0 = blockIdx.x * BQ;
    const size_t base  = (size_t)b * TD * CD + (size_t)h * DH;
    const size_t vbase = (size_t)(b * NH + h) * DH * TD;

    // Q frags (N-side of S^T mfma): lane holds Q[q=l16][d=quad*8+j]
    bf16x8 qf[2][2];
    #pragma unroll
    for (int rt = 0; rt < 2; ++rt) {
        const short* qp = q + base + (size_t)(q0 + w * 32 + rt * 16 + l16) * CD;
        qf[rt][0] = *(const bf16x8*)&qp[quad * 8];
        qf[rt][1] = *(const bf16x8*)&qp[32 + quad * 8];
    }

    float l_p[2] = {};   // per-lane: q = q0+w*32+rt*16+l16, keys quad*4+reg
    f32x4 O[2][4] = {};

    const int kbeg = split * (TD / 2);
    const int NTI = (TD / 2) / BK;   // 16, even

    // per-lane staging coords: rows r8 / r8+32, cols c8..c8+7
    const int r8 = tid >> 3, c8 = (tid & 7) * 8;
    const short* kg = k + base + c8;                       // + (kt+row)*CD
    const short* vg = vt + vbase + (size_t)r8 * TD + c8;   // + kt (+32*TD)

#define ISSUE_T(t, K0, K1, V0, V1) do {                                   \
        const size_t ko_ = (size_t)(kbeg + (t) * BK);                     \
        K0 = *(const bf16x8*)&kg[(ko_ + r8) * CD];                        \
        K1 = *(const bf16x8*)&kg[(ko_ + r8 + 32) * CD];                   \
        V0 = *(const bf16x8*)&vg[ko_];                                    \
        V1 = *(const bf16x8*)&vg[(size_t)32 * TD + ko_];                  \
    } while (0)

#define WRITE_T(buf, K0, K1, V0, V1) do {                                 \
        *(bf16x8*)&Ks[buf][r8 * STR + c8] = K0;                           \
        *(bf16x8*)&Ks[buf][(r8 + 32) * STR + c8] = K1;                    \
        *(bf16x8*)&Vt[buf][r8 * STR + c8] = V0;                           \
        *(bf16x8*)&Vt[buf][(r8 + 32) * STR + c8] = V1;                    \
    } while (0)

#define COMPUTE_T(buf) do {                                               \
        __builtin_amdgcn_s_setprio(1);                                    \
        _Pragma("unroll")                                                 \
        for (int ct = 0; ct < 4; ++ct) {                                  \
            bf16x8 kb0 = *(const bf16x8*)&Ks[buf][(ct * 16 + l16) * STR + quad * 8]; \
            bf16x8 kb1 = *(const bf16x8*)&Ks[buf][(ct * 16 + l16) * STR + 32 + quad * 8]; \
            bf16x4 pa[2];                                                 \
            _Pragma("unroll")                                             \
            for (int rt = 0; rt < 2; ++rt) {                              \
                f32x4 acc = (f32x4){0.f, 0.f, 0.f, 0.f};                  \
                acc = __builtin_amdgcn_mfma_f32_16x16x32_bf16(kb0, qf[rt][0], acc, 0, 0, 0); \
                acc = __builtin_amdgcn_mfma_f32_16x16x32_bf16(kb1, qf[rt][1], acc, 0, 0, 0); \
                float p0 = EXP2(acc[0]), p1 = EXP2(acc[1]);               \
                float p2 = EXP2(acc[2]), p3 = EXP2(acc[3]);               \
                l_p[rt] += (p0 + p1) + (p2 + p3);                         \
                union { u32x2 u; bf16x4 s; } cv_;                         \
                cv_.u = (u32x2){pk2bf(p0, p1), pk2bf(p2, p3)};            \
                pa[rt] = cv_.s;                                           \
            }                                                             \
            _Pragma("unroll")                                             \
            for (int dt = 0; dt < 4; ++dt) {                              \
                bf16x4 vb = *(const bf16x4*)&Vt[buf][(dt * 16 + l16) * STR + ct * 16 + quad * 4]; \
                O[0][dt] = MFMA16x16(pa[0], vb, O[0][dt]);                \
                O[1][dt] = MFMA16x16(pa[1], vb, O[1][dt]);                \
            }                                                             \
        }                                                                 \
        __builtin_amdgcn_s_setprio(0);                                    \
    } while (0)

    bf16x8 kA0, kA1, vA0, vA1;   // set A: odd tiles
    bf16x8 kB0, kB1, vB0, vB1;   // set B: even tiles

    // prologue: tile 0 direct to LDS[0] (one exposed latency), tile 1 -> A
    ISSUE_T(0, kA0, kA1, vA0, vA1);
    WRITE_T(0, kA0, kA1, vA0, vA1);
    ISSUE_T(1, kA0, kA1, vA0, vA1);
    __syncthreads();

    for (int it = 0; it < NTI; it += 2) {
        // tile it (LDS[0]); A holds tile it+1
        if (it + 2 < NTI) ISSUE_T(it + 2, kB0, kB1, vB0, vB1);
        COMPUTE_T(0);
        WRITE_T(1, kA0, kA1, vA0, vA1);
        __syncthreads();
        // tile it+1 (LDS[1]); B holds tile it+2
        if (it + 3 < NTI) ISSUE_T(it + 3, kA0, kA1, vA0, vA1);
        COMPUTE_T(1);
        if (it + 2 < NTI) WRITE_T(0, kB0, kB1, vB0, vB1);
        __syncthreads();
    }
#undef ISSUE_T
#undef WRITE_T
#undef COMPUTE_T

    // epilogue: unnormalized O (bf16) + l (fp32) per split
    short* osp = opart + (size_t)split * BT * CD;
    float* lsp = lpart + (size_t)split * BB * NH * TD + (size_t)(b * NH + h) * TD;
    #pragma unroll
    for (int rt = 0; rt < 2; ++rt) {
        float l = l_p[rt];
        l += __shfl_xor(l, 16, 64);
        l += __shfl_xor(l, 32, 64);
        if (lane < 16) lsp[q0 + w * 32 + rt * 16 + lane] = l;
        #pragma unroll
        for (int reg = 0; reg < 4; ++reg) {
            int row = q0 + w * 32 + rt * 16 + quad * 4 + reg;
            short* op = osp + base + (size_t)row * CD;
            #pragma unroll
            for (int dt = 0; dt < 4; ++dt)
                op[dt * 16 + l16] = f2bf(O[rt][dt][reg]);
        }
    }
}

// ---------------- Combine split-K partials: ob = (O0+O1)/(l0+l1), bf16 -------
__launch_bounds__(256)
__global__ void attn_combine(const short* __restrict__ opart,
                             const float* __restrict__ lpart,
                             short* __restrict__ ob) {
    const size_t idx = ((size_t)blockIdx.x * 256 + threadIdx.x) * 8;
    const int row = (int)(idx >> 10);        // / CD
    const int col = (int)(idx & 1023);
    const int b = row >> 11, qq = row & (TD - 1), hh = col >> 6;
    const size_t lbase = (size_t)(b * NH + hh) * TD + qq;
    const float l0 = lpart[lbase];
    const float l1 = lpart[(size_t)BB * NH * TD + lbase];
    const float inv = 1.f / (l0 + l1);
    bf16x8 a = *(const bf16x8*)&opart[idx];
    bf16x8 c = *(const bf16x8*)&opart[(size_t)BT * CD + idx];
    bf16x8 r;
    #pragma unroll
    for (int j = 0; j < 8; ++j)
        r[j] = f2bf((bf2f(a[j]) + bf2f(c[j])) * inv);
    *(bf16x8*)&ob[idx] = r;
}

extern "C" void kernel_launch(void* const* d_in, const int* in_sizes, int n_in,
                              void* d_out, int out_size, void* d_ws, size_t ws_size,
                              hipStream_t stream) {
    const float* x   = (const float*)d_in[0];
    const float* Wq  = (const float*)d_in[1];
    const float* Wk  = (const float*)d_in[2];
    const float* Wv  = (const float*)d_in[3];
    const float* Wo  = (const float*)d_in[4];
    const float* bo  = (const float*)d_in[5];
    const float* W1  = (const float*)d_in[6];
    const float* b1  = (const float*)d_in[7];
    const float* W2  = (const float*)d_in[8];
    const float* b2  = (const float*)d_in[9];
    const float* g1  = (const float*)d_in[10];
    const float* be1 = (const float*)d_in[11];
    const float* g2  = (const float*)d_in[12];
    const float* be2 = (const float*)d_in[13];
    float* out = (float*)d_out;

    const size_t SZ = (size_t)BT * CD;  // 4M elements
    float* ws  = (float*)d_ws;
    short* qbf = (short*)ws;                       // [0,1.5SZ): q|k|v bf16
    short* kbf = qbf + SZ;
    short* vbf = qbf + 2 * SZ;
    float* lpart = ws + SZ + SZ / 2;               // [1.5SZ,+128K floats)
    short* opart = (short*)(ws + 2 * SZ);          // [2SZ,3SZ): 2 x SZ bf16
    float* x1  = ws + 2 * SZ;                      // [2SZ,3SZ): after combine
    short* h   = (short*)(ws + 3 * SZ);            // [3SZ,3.5SZ)
    short* ob  = (short*)(ws + 3 * SZ + SZ / 2);   // [3.5SZ,4SZ)
    short* wqt = (short*)(ws + 4 * SZ);            // [4SZ,4.5SZ): 3xCD*CD + CD*CD
    short* wot = wqt + 3 * CD * CD;
    short* w1t = (short*)(ws + 4 * SZ + SZ / 2);   // [4.5SZ,5SZ)
    short* w2t = (short*)(ws + 5 * SZ);            // [5SZ,5.5SZ)
    short* vtg = (short*)(ws + 5 * SZ + SZ / 2);   // [5.5SZ,6SZ): V^T global
    short* ff1 = (short*)ws;                       // [0,2SZ): reuses dead q/k/v

    // 1) h1 = LN(x)  (bf16)
    ln_kernel<<<BT, 256, 0, stream>>>(x, g1, be1, h);

    // 2) all weight transposes fused (bf16 B^T layouts)
    prep_weights<<<3072, 256, 0, stream>>>(Wq, Wk, Wv, Wo, W1, W2, wqt, wot, w1t, w2t);

    // 3) merged q|k|v = h1 @ [Wq|Wk|Wv]  (bf16; C^-0.5*log2e folded into q)
    gemm_mfma<5, 128><<<dim3(24, 32), 256, 0, stream>>>(h, wqt, nullptr, nullptr, nullptr, qbf, 3 * CD, CD);

    // 4) vtg = V^T per (b,h)
    vtrans<<<dim3(TD / 64, 2 * NH), 256, 0, stream>>>(vbf, vtg);

    // 5) attention split-K -> opart, lpart
    attn_mfma<<<dim3(TD / BQ, NH, BB * 2), 256, 0, stream>>>(qbf, kbf, vtg, opart, lpart);

    // 6) combine -> ob (bf16, concat-head layout)
    attn_combine<<<dim3((int)(SZ / (256 * 8))), 256, 0, stream>>>(opart, lpart, ob);

    // 7) x1 = ob @ Wo + bo + x  (fp32; 128x128 tile: LDS-read per MFMA halved)
    gemm_mfma<1, 128><<<dim3(8, 32), 256, 0, stream>>>(ob, wot, bo, x, x1, nullptr, CD, CD);

    // 8) h2 = LN(x1)  (bf16)
    ln_kernel<<<BT, 256, 0, stream>>>(x1, g2, be2, h);

    // 9) ff1 = relu(h2 @ W1 + b1)  (bf16, N=4096)
    gemm_mfma<2, 128><<<dim3(32, 32), 256, 0, stream>>>(h, w1t, b1, nullptr, nullptr, ff1, 4 * CD, CD);

    // 10) out = ff1 @ W2 + b2 + x1  (fp32, K=4096, 128x128 tile)
    gemm_mfma<1, 128><<<dim3(8, 32), 256, 0, stream>>>(ff1, w2t, b2, x1, out, nullptr, CD, 4 * CD);
}

// Round 3
// 381.018 us; speedup vs baseline: 1.1774x; 1.0909x over previous
//
#include <hip/hip_runtime.h>
#include <hip/hip_bf16.h>

#define BT   4096   // B*T
#define CD   1024   // C
#define TD   2048   // T
#define NH   16     // heads
#define DH   64     // head dim
#define BB   2      // batch

typedef __attribute__((ext_vector_type(8))) short bf16x8;
typedef __attribute__((ext_vector_type(4))) short bf16x4;
typedef __attribute__((ext_vector_type(4))) float f32x4;
typedef __attribute__((ext_vector_type(2))) unsigned int u32x2;

__device__ inline short f2bf(float f) {
    union { float fv; unsigned u; } x; x.fv = f;
    unsigned r = x.u + 0x7fffu + ((x.u >> 16) & 1u);
    return (short)(r >> 16);
}
__device__ inline float bf2f(short s) {
    union { unsigned u; float f; } x; x.u = ((unsigned)(unsigned short)s) << 16;
    return x.f;
}
__device__ inline unsigned pk2bf(float a, float b) {
    union { __hip_bfloat162 h; unsigned u; } cv;
    cv.h = __float22bfloat162_rn(float2{a, b});
    return cv.u;
}

// raw v_exp_f32 (2^x): avoid any OCML guard sequence
#if __has_builtin(__builtin_amdgcn_exp2f)
#define EXP2(x) __builtin_amdgcn_exp2f(x)
#else
#define EXP2(x) exp2f(x)
#endif

// K=16 bf16 MFMA: A-frag layout (lane: m=l16, k=quad*4+j) is bit-identical to
// the 16x16 C-layout (m=quad*4+reg, n=l16) of the swapped S^T MFMA -> P stays
// in registers for PV (no LDS round-trip).
#if __has_builtin(__builtin_amdgcn_mfma_f32_16x16x16bf16_1k)
#define MFMA16x16(a, b, c) __builtin_amdgcn_mfma_f32_16x16x16bf16_1k(a, b, c, 0, 0, 0)
#elif __has_builtin(__builtin_amdgcn_mfma_f32_16x16x16_bf16)
#define MFMA16x16(a, b, c) __builtin_amdgcn_mfma_f32_16x16x16_bf16(a, b, c, 0, 0, 0)
#else
__device__ inline f32x4 mfma16_asm(bf16x4 a, bf16x4 b, f32x4 c) {
    f32x4 d;
    asm volatile("v_mfma_f32_16x16x16_bf16 %0, %1, %2, %3"
                 : "=v"(d) : "v"(a), "v"(b), "v"(c));
    return d;
}
#define MFMA16x16(a, b, c) mfma16_asm(a, b, c)
#endif

__device__ inline void gload_lds16(const short* g, short* lds) {
    __builtin_amdgcn_global_load_lds(
        (const __attribute__((address_space(1))) void*)g,
        (__attribute__((address_space(3))) void*)lds, 16, 0, 0);
}

// ---------------- LayerNorm: one block per row (C=1024), fp32 in, bf16 out ----
__launch_bounds__(256)
__global__ void ln_kernel(const float* __restrict__ x,
                          const float* __restrict__ g,
                          const float* __restrict__ be,
                          short* __restrict__ out) {
    __shared__ float red[2][4];
    const int row = blockIdx.x;
    const float* xr = x + (size_t)row * CD;
    float s = 0.f, ss = 0.f;
    for (int c = threadIdx.x; c < CD; c += 256) {
        float v = xr[c];
        s += v; ss += v * v;
    }
    #pragma unroll
    for (int off = 32; off > 0; off >>= 1) {
        s  += __shfl_down(s,  off, 64);
        ss += __shfl_down(ss, off, 64);
    }
    int wid = threadIdx.x >> 6, lane = threadIdx.x & 63;
    if (lane == 0) { red[0][wid] = s; red[1][wid] = ss; }
    __syncthreads();
    float sum   = red[0][0] + red[0][1] + red[0][2] + red[0][3];
    float sumsq = red[1][0] + red[1][1] + red[1][2] + red[1][3];
    float mu   = sum * (1.f / CD);
    float var  = sumsq * (1.f / CD) - mu * mu;
    float rstd = rsqrtf(var + 1e-5f);
    short* orow = out + (size_t)row * CD;
    for (int c = threadIdx.x; c < CD; c += 256) {
        float v = xr[c];
        orow[c] = f2bf((v - mu) * rstd * g[c] + be[c]);
    }
}

// ------------- Fused weight prep: all 64x64 fp32->bf16 transpose tiles -------
// blocks 0..767: Wq/Wk/Wv (per-head CDxDH slices) -> wqt (3,H,DH,C)
// 768..1023: Wo (CDxCD); 1024..2047: W1 (CDx4CD); 2048..3071: W2 (4CDxCD)
__launch_bounds__(256)
__global__ void prep_weights(const float* __restrict__ Wq, const float* __restrict__ Wk,
                             const float* __restrict__ Wv, const float* __restrict__ Wo,
                             const float* __restrict__ W1, const float* __restrict__ W2,
                             short* __restrict__ wqt, short* __restrict__ wot,
                             short* __restrict__ w1t, short* __restrict__ w2t) {
    __shared__ float tt[64][65];
    const int id = blockIdx.x;
    const float* in; short* out; int R, Cc, r0, c0;
    if (id < 768) {
        int which = id >> 8, rem = id & 255, hh = rem >> 4, ry = rem & 15;
        in  = (which == 0 ? Wq : which == 1 ? Wk : Wv) + (size_t)hh * CD * DH;
        out = wqt + (size_t)which * CD * CD + (size_t)hh * DH * CD;
        R = CD; Cc = DH; r0 = ry * 64; c0 = 0;
    } else if (id < 1024) {
        int t = id - 768;  in = Wo; out = wot; R = CD;     Cc = CD;     r0 = (t >> 4) * 64; c0 = (t & 15) * 64;
    } else if (id < 2048) {
        int t = id - 1024; in = W1; out = w1t; R = CD;     Cc = 4 * CD; r0 = (t >> 6) * 64; c0 = (t & 63) * 64;
    } else {
        int t = id - 2048; in = W2; out = w2t; R = 4 * CD; Cc = CD;     r0 = (t >> 4) * 64; c0 = (t & 15) * 64;
    }
    const int tid = threadIdx.x;
    #pragma unroll
    for (int i = 0; i < 16; ++i) {
        int e = i * 256 + tid;
        tt[e >> 6][e & 63] = in[(size_t)(r0 + (e >> 6)) * Cc + c0 + (e & 63)];
    }
    __syncthreads();
    #pragma unroll
    for (int i = 0; i < 16; ++i) {
        int e = i * 256 + tid;
        out[(size_t)(c0 + (e >> 6)) * R + r0 + (e & 63)] = f2bf(tt[e & 63][e >> 6]);
    }
}

// ------------- V transpose: vbf (BT x C bf16) -> vtg[b][h][d][t] bf16 -------
__launch_bounds__(256)
__global__ void vtrans(const short* __restrict__ vin, short* __restrict__ vout) {
    __shared__ short t[64 * 65];
    const int tid = threadIdx.x;
    const int bh = blockIdx.y;
    const int t0 = blockIdx.x * 64;
    const int b = bh >> 4, h = bh & 15;
    const short* src = vin + (size_t)b * TD * CD + (size_t)h * DH;
    short* dst = vout + (size_t)bh * DH * TD;
    #pragma unroll
    for (int i = 0; i < 16; ++i) {
        int e = i * 256 + tid;
        t[(e >> 6) * 65 + (e & 63)] = src[(size_t)(t0 + (e >> 6)) * CD + (e & 63)];
    }
    __syncthreads();
    #pragma unroll
    for (int i = 0; i < 16; ++i) {
        int e = i * 256 + tid;
        int d = e >> 6, tt = e & 63;
        dst[(size_t)d * TD + t0 + tt] = t[tt * 65 + d];
    }
}

// ---------------- MFMA GEMM: C(128 x TN) = A(M x K) . Bt(N x K)^T, bf16 ------
// R12: triple-buffered LDS + counted vmcnt(4) + raw barriers (loads for tile
// t+2 stay in flight across the barrier; never drain in steady state), and
// XOR-swizzled 16B slots (source k-chunk ^= (row>>1)&3, read ^= (l16>>1)&3)
// -> fragment ds_read_b128 is bank-conflict-free while gload_lds dest stays
// linear (T21: swizzle both sides via source permutation).
// MODE 1: + bias + fp32 resid -> fp32 out
// MODE 2: + bias, relu -> bf16 out
// MODE 5: QKV merged: N=3072; seg=col>>10 -> outb + seg*BT*CD; seg0 scaled by
//         C^-0.5 * log2(e)  (attention uses exp2)
template <int MODE, int TN>
__launch_bounds__(256)
__global__ void gemm_mfma(const short* __restrict__ A,
                          const short* __restrict__ Bt,
                          const float* __restrict__ bias,
                          const float* __restrict__ resid,
                          float* __restrict__ outf,
                          short* __restrict__ outb,
                          int N, int K) {
    __shared__ short As[3][128 * 32];
    __shared__ short Bs[3][TN * 32];
    const int tid = threadIdx.x;
    const int w = tid >> 6, lane = tid & 63;
    const int quad = lane >> 4, l16 = lane & 15;
    const int wr = w >> 1, wc = w & 1;
    const int m0 = blockIdx.y * 128, n0 = blockIdx.x * TN;
    const int NT = TN / 32;

    f32x4 acc[4][NT] = {};

    auto STAGE = [&](int kt, int bi) {
        const int k0 = kt * 32;
        #pragma unroll
        for (int i = 0; i < 2; ++i) {
            int s = i * 256 + tid;
            int row = s >> 2, kc = (s & 3) ^ ((row >> 1) & 3);
            gload_lds16(A + (size_t)(m0 + row) * K + k0 + kc * 8,
                        &As[bi][(i * 256 + w * 64) * 8]);
        }
        #pragma unroll
        for (int i = 0; i < TN / 64; ++i) {
            int s = i * 256 + tid;
            int row = s >> 2, kc = (s & 3) ^ ((row >> 1) & 3);
            gload_lds16(Bt + (size_t)(n0 + row) * K + k0 + kc * 8,
                        &Bs[bi][(i * 256 + w * 64) * 8]);
        }
    };

    auto COMPUTE = [&](int bi) {
        const int xo = (quad ^ ((l16 >> 1) & 3)) * 8;
        bf16x8 a[4], b[NT];
        #pragma unroll
        for (int mt = 0; mt < 4; ++mt)
            a[mt] = *(const bf16x8*)&As[bi][(wr * 64 + mt * 16 + l16) * 32 + xo];
        #pragma unroll
        for (int nt = 0; nt < NT; ++nt)
            b[nt] = *(const bf16x8*)&Bs[bi][(wc * (TN / 2) + nt * 16 + l16) * 32 + xo];
        #pragma unroll
        for (int mt = 0; mt < 4; ++mt)
            #pragma unroll
            for (int nt = 0; nt < NT; ++nt)
                acc[mt][nt] = __builtin_amdgcn_mfma_f32_16x16x32_bf16(a[mt], b[nt], acc[mt][nt], 0, 0, 0);
    };

    const int nk = K >> 5;
    // prologue: tiles 0,1 in flight (4 + 4 loads per lane for TN=128)
    STAGE(0, 0);
    STAGE(1, 1);
    int bi = 0;
    for (int t = 0; t < nk - 1; ++t) {
        // counted wait: tile t's loads done; tile t+1's (youngest 4) may fly
        if (TN == 128) asm volatile("s_waitcnt vmcnt(4)" ::: "memory");
        else           asm volatile("s_waitcnt vmcnt(3)" ::: "memory");
        __builtin_amdgcn_s_barrier();
        asm volatile("" ::: "memory");
        int bn = bi + 2 >= 3 ? bi - 1 : bi + 2;
        if (t + 2 < nk) STAGE(t + 2, bn);
        COMPUTE(bi);
        bi = bi + 1 >= 3 ? 0 : bi + 1;
    }
    asm volatile("s_waitcnt vmcnt(0)" ::: "memory");
    __builtin_amdgcn_s_barrier();
    asm volatile("" ::: "memory");
    COMPUTE(bi);

    const float qsc = (MODE == 5 && n0 < CD) ? 0.03125f * 1.44269504f : 1.0f;
    short* ob5 = (MODE == 5) ? outb + (size_t)(n0 >> 10) * BT * CD : nullptr;

    #pragma unroll
    for (int mt = 0; mt < 4; ++mt)
        #pragma unroll
        for (int nt = 0; nt < NT; ++nt)
            #pragma unroll
            for (int reg = 0; reg < 4; ++reg) {
                int row = m0 + wr * 64 + mt * 16 + quad * 4 + reg;
                int col = n0 + wc * (TN / 2) + nt * 16 + l16;
                float v = acc[mt][nt][reg];
                if (MODE == 1) { v += bias[col] + resid[(size_t)row * N + col];
                                 outf[(size_t)row * N + col] = v; }
                if (MODE == 2) { v = fmaxf(v + bias[col], 0.f);
                                 outb[(size_t)row * N + col] = f2bf(v); }
                if (MODE == 5) { ob5[(size_t)row * CD + (col & 1023)] = f2bf(v * qsc); }
            }
}

// ---------------- Flash attention, split-K, MFMA bf16, no-max softmax --------
//  * 2-tile-deep register prefetch; counted vmcnt derived by compiler.
//  * STR 68: conflict-free for all access patterns; LDS 34816 B.
//  * setprio(1) around the MFMA/exp2 compute cluster; raw v_exp_f32.
#define BQ   128
#define BK   64
#define STR  68

__launch_bounds__(256)
__global__ void attn_mfma(const short* __restrict__ q,
                          const short* __restrict__ k,
                          const short* __restrict__ vt,
                          short* __restrict__ opart,
                          float* __restrict__ lpart) {
    __shared__ short Ks[2][BK * STR];
    __shared__ short Vt[2][DH * STR];

    const int tid  = threadIdx.x;
    const int w = tid >> 6, lane = tid & 63;
    const int quad = lane >> 4, l16 = lane & 15;
    const int h = blockIdx.y;
    const int b = blockIdx.z >> 1, split = blockIdx.z & 1;
    const int q0 = blockIdx.x * BQ;
    const size_t base  = (size_t)b * TD * CD + (size_t)h * DH;
    const size_t vbase = (size_t)(b * NH + h) * DH * TD;

    // Q frags (N-side of S^T mfma): lane holds Q[q=l16][d=quad*8+j]
    bf16x8 qf[2][2];
    #pragma unroll
    for (int rt = 0; rt < 2; ++rt) {
        const short* qp = q + base + (size_t)(q0 + w * 32 + rt * 16 + l16) * CD;
        qf[rt][0] = *(const bf16x8*)&qp[quad * 8];
        qf[rt][1] = *(const bf16x8*)&qp[32 + quad * 8];
    }

    float l_p[2] = {};   // per-lane: q = q0+w*32+rt*16+l16, keys quad*4+reg
    f32x4 O[2][4] = {};

    const int kbeg = split * (TD / 2);
    const int NTI = (TD / 2) / BK;   // 16, even

    // per-lane staging coords: rows r8 / r8+32, cols c8..c8+7
    const int r8 = tid >> 3, c8 = (tid & 7) * 8;
    const short* kg = k + base + c8;                       // + (kt+row)*CD
    const short* vg = vt + vbase + (size_t)r8 * TD + c8;   // + kt (+32*TD)

#define ISSUE_T(t, K0, K1, V0, V1) do {                                   \
        const size_t ko_ = (size_t)(kbeg + (t) * BK);                     \
        K0 = *(const bf16x8*)&kg[(ko_ + r8) * CD];                        \
        K1 = *(const bf16x8*)&kg[(ko_ + r8 + 32) * CD];                   \
        V0 = *(const bf16x8*)&vg[ko_];                                    \
        V1 = *(const bf16x8*)&vg[(size_t)32 * TD + ko_];                  \
    } while (0)

#define WRITE_T(buf, K0, K1, V0, V1) do {                                 \
        *(bf16x8*)&Ks[buf][r8 * STR + c8] = K0;                           \
        *(bf16x8*)&Ks[buf][(r8 + 32) * STR + c8] = K1;                    \
        *(bf16x8*)&Vt[buf][r8 * STR + c8] = V0;                           \
        *(bf16x8*)&Vt[buf][(r8 + 32) * STR + c8] = V1;                    \
    } while (0)

#define COMPUTE_T(buf) do {                                               \
        __builtin_amdgcn_s_setprio(1);                                    \
        _Pragma("unroll")                                                 \
        for (int ct = 0; ct < 4; ++ct) {                                  \
            bf16x8 kb0 = *(const bf16x8*)&Ks[buf][(ct * 16 + l16) * STR + quad * 8]; \
            bf16x8 kb1 = *(const bf16x8*)&Ks[buf][(ct * 16 + l16) * STR + 32 + quad * 8]; \
            bf16x4 pa[2];                                                 \
            _Pragma("unroll")                                             \
            for (int rt = 0; rt < 2; ++rt) {                              \
                f32x4 acc = (f32x4){0.f, 0.f, 0.f, 0.f};                  \
                acc = __builtin_amdgcn_mfma_f32_16x16x32_bf16(kb0, qf[rt][0], acc, 0, 0, 0); \
                acc = __builtin_amdgcn_mfma_f32_16x16x32_bf16(kb1, qf[rt][1], acc, 0, 0, 0); \
                float p0 = EXP2(acc[0]), p1 = EXP2(acc[1]);               \
                float p2 = EXP2(acc[2]), p3 = EXP2(acc[3]);               \
                l_p[rt] += (p0 + p1) + (p2 + p3);                         \
                union { u32x2 u; bf16x4 s; } cv_;                         \
                cv_.u = (u32x2){pk2bf(p0, p1), pk2bf(p2, p3)};            \
                pa[rt] = cv_.s;                                           \
            }                                                             \
            _Pragma("unroll")                                             \
            for (int dt = 0; dt < 4; ++dt) {                              \
                bf16x4 vb = *(const bf16x4*)&Vt[buf][(dt * 16 + l16) * STR + ct * 16 + quad * 4]; \
                O[0][dt] = MFMA16x16(pa[0], vb, O[0][dt]);                \
                O[1][dt] = MFMA16x16(pa[1], vb, O[1][dt]);                \
            }                                                             \
        }                                                                 \
        __builtin_amdgcn_s_setprio(0);                                    \
    } while (0)

    bf16x8 kA0, kA1, vA0, vA1;   // set A: odd tiles
    bf16x8 kB0, kB1, vB0, vB1;   // set B: even tiles

    // prologue: tile 0 direct to LDS[0] (one exposed latency), tile 1 -> A
    ISSUE_T(0, kA0, kA1, vA0, vA1);
    WRITE_T(0, kA0, kA1, vA0, vA1);
    ISSUE_T(1, kA0, kA1, vA0, vA1);
    __syncthreads();

    for (int it = 0; it < NTI; it += 2) {
        // tile it (LDS[0]); A holds tile it+1
        if (it + 2 < NTI) ISSUE_T(it + 2, kB0, kB1, vB0, vB1);
        COMPUTE_T(0);
        WRITE_T(1, kA0, kA1, vA0, vA1);
        __syncthreads();
        // tile it+1 (LDS[1]); B holds tile it+2
        if (it + 3 < NTI) ISSUE_T(it + 3, kA0, kA1, vA0, vA1);
        COMPUTE_T(1);
        if (it + 2 < NTI) WRITE_T(0, kB0, kB1, vB0, vB1);
        __syncthreads();
    }
#undef ISSUE_T
#undef WRITE_T
#undef COMPUTE_T

    // epilogue: unnormalized O (bf16) + l (fp32) per split
    short* osp = opart + (size_t)split * BT * CD;
    float* lsp = lpart + (size_t)split * BB * NH * TD + (size_t)(b * NH + h) * TD;
    #pragma unroll
    for (int rt = 0; rt < 2; ++rt) {
        float l = l_p[rt];
        l += __shfl_xor(l, 16, 64);
        l += __shfl_xor(l, 32, 64);
        if (lane < 16) lsp[q0 + w * 32 + rt * 16 + lane] = l;
        #pragma unroll
        for (int reg = 0; reg < 4; ++reg) {
            int row = q0 + w * 32 + rt * 16 + quad * 4 + reg;
            short* op = osp + base + (size_t)row * CD;
            #pragma unroll
            for (int dt = 0; dt < 4; ++dt)
                op[dt * 16 + l16] = f2bf(O[rt][dt][reg]);
        }
    }
}

// ---------------- Combine split-K partials: ob = (O0+O1)/(l0+l1), bf16 -------
__launch_bounds__(256)
__global__ void attn_combine(const short* __restrict__ opart,
                             const float* __restrict__ lpart,
                             short* __restrict__ ob) {
    const size_t idx = ((size_t)blockIdx.x * 256 + threadIdx.x) * 8;
    const int row = (int)(idx >> 10);        // / CD
    const int col = (int)(idx & 1023);
    const int b = row >> 11, qq = row & (TD - 1), hh = col >> 6;
    const size_t lbase = (size_t)(b * NH + hh) * TD + qq;
    const float l0 = lpart[lbase];
    const float l1 = lpart[(size_t)BB * NH * TD + lbase];
    const float inv = 1.f / (l0 + l1);
    bf16x8 a = *(const bf16x8*)&opart[idx];
    bf16x8 c = *(const bf16x8*)&opart[(size_t)BT * CD + idx];
    bf16x8 r;
    #pragma unroll
    for (int j = 0; j < 8; ++j)
        r[j] = f2bf((bf2f(a[j]) + bf2f(c[j])) * inv);
    *(bf16x8*)&ob[idx] = r;
}

extern "C" void kernel_launch(void* const* d_in, const int* in_sizes, int n_in,
                              void* d_out, int out_size, void* d_ws, size_t ws_size,
                              hipStream_t stream) {
    const float* x   = (const float*)d_in[0];
    const float* Wq  = (const float*)d_in[1];
    const float* Wk  = (const float*)d_in[2];
    const float* Wv  = (const float*)d_in[3];
    const float* Wo  = (const float*)d_in[4];
    const float* bo  = (const float*)d_in[5];
    const float* W1  = (const float*)d_in[6];
    const float* b1  = (const float*)d_in[7];
    const float* W2  = (const float*)d_in[8];
    const float* b2  = (const float*)d_in[9];
    const float* g1  = (const float*)d_in[10];
    const float* be1 = (const float*)d_in[11];
    const float* g2  = (const float*)d_in[12];
    const float* be2 = (const float*)d_in[13];
    float* out = (float*)d_out;

    const size_t SZ = (size_t)BT * CD;  // 4M elements
    float* ws  = (float*)d_ws;
    short* qbf = (short*)ws;                       // [0,1.5SZ): q|k|v bf16
    short* kbf = qbf + SZ;
    short* vbf = qbf + 2 * SZ;
    float* lpart = ws + SZ + SZ / 2;               // [1.5SZ,+128K floats)
    short* opart = (short*)(ws + 2 * SZ);          // [2SZ,3SZ): 2 x SZ bf16
    float* x1  = ws + 2 * SZ;                      // [2SZ,3SZ): after combine
    short* h   = (short*)(ws + 3 * SZ);            // [3SZ,3.5SZ)
    short* ob  = (short*)(ws + 3 * SZ + SZ / 2);   // [3.5SZ,4SZ)
    short* wqt = (short*)(ws + 4 * SZ);            // [4SZ,4.5SZ): 3xCD*CD + CD*CD
    short* wot = wqt + 3 * CD * CD;
    short* w1t = (short*)(ws + 4 * SZ + SZ / 2);   // [4.5SZ,5SZ)
    short* w2t = (short*)(ws + 5 * SZ);            // [5SZ,5.5SZ)
    short* vtg = (short*)(ws + 5 * SZ + SZ / 2);   // [5.5SZ,6SZ): V^T global
    short* ff1 = (short*)ws;                       // [0,2SZ): reuses dead q/k/v

    // 1) h1 = LN(x)  (bf16)
    ln_kernel<<<BT, 256, 0, stream>>>(x, g1, be1, h);

    // 2) all weight transposes fused (bf16 B^T layouts)
    prep_weights<<<3072, 256, 0, stream>>>(Wq, Wk, Wv, Wo, W1, W2, wqt, wot, w1t, w2t);

    // 3) merged q|k|v = h1 @ [Wq|Wk|Wv]  (bf16; C^-0.5*log2e folded into q)
    gemm_mfma<5, 128><<<dim3(24, 32), 256, 0, stream>>>(h, wqt, nullptr, nullptr, nullptr, qbf, 3 * CD, CD);

    // 4) vtg = V^T per (b,h)
    vtrans<<<dim3(TD / 64, 2 * NH), 256, 0, stream>>>(vbf, vtg);

    // 5) attention split-K -> opart, lpart
    attn_mfma<<<dim3(TD / BQ, NH, BB * 2), 256, 0, stream>>>(qbf, kbf, vtg, opart, lpart);

    // 6) combine -> ob (bf16, concat-head layout)
    attn_combine<<<dim3((int)(SZ / (256 * 8))), 256, 0, stream>>>(opart, lpart, ob);

    // 7) x1 = ob @ Wo + bo + x  (fp32)
    gemm_mfma<1, 128><<<dim3(8, 32), 256, 0, stream>>>(ob, wot, bo, x, x1, nullptr, CD, CD);

    // 8) h2 = LN(x1)  (bf16)
    ln_kernel<<<BT, 256, 0, stream>>>(x1, g2, be2, h);

    // 9) ff1 = relu(h2 @ W1 + b1)  (bf16, N=4096)
    gemm_mfma<2, 128><<<dim3(32, 32), 256, 0, stream>>>(h, w1t, b1, nullptr, nullptr, ff1, 4 * CD, CD);

    // 10) out = ff1 @ W2 + b2 + x1  (fp32, K=4096)
    gemm_mfma<1, 128><<<dim3(8, 32), 256, 0, stream>>>(ff1, w2t, b2, x1, out, nullptr, CD, 4 * CD);
}

// Round 4
// 340.852 us; speedup vs baseline: 1.3161x; 1.1178x over previous
//
#include <hip/hip_runtime.h>
#include <hip/hip_bf16.h>

#define BT   4096   // B*T
#define CD   1024   // C
#define TD   2048   // T
#define NH   16     // heads
#define DH   64     // head dim
#define BB   2      // batch

typedef __attribute__((ext_vector_type(8))) short bf16x8;
typedef __attribute__((ext_vector_type(4))) short bf16x4;
typedef __attribute__((ext_vector_type(4))) float f32x4;
typedef __attribute__((ext_vector_type(2))) unsigned int u32x2;

__device__ inline short f2bf(float f) {
    union { float fv; unsigned u; } x; x.fv = f;
    unsigned r = x.u + 0x7fffu + ((x.u >> 16) & 1u);
    return (short)(r >> 16);
}
__device__ inline float bf2f(short s) {
    union { unsigned u; float f; } x; x.u = ((unsigned)(unsigned short)s) << 16;
    return x.f;
}
__device__ inline unsigned pk2bf(float a, float b) {
    union { __hip_bfloat162 h; unsigned u; } cv;
    cv.h = __float22bfloat162_rn(float2{a, b});
    return cv.u;
}

// raw v_exp_f32 (2^x): avoid any OCML guard sequence
#if __has_builtin(__builtin_amdgcn_exp2f)
#define EXP2(x) __builtin_amdgcn_exp2f(x)
#else
#define EXP2(x) exp2f(x)
#endif

// K=16 bf16 MFMA: A-frag layout (lane: m=l16, k=quad*4+j) is bit-identical to
// the 16x16 C-layout (m=quad*4+reg, n=l16) of the swapped S^T MFMA -> P stays
// in registers for PV (no LDS round-trip).
#if __has_builtin(__builtin_amdgcn_mfma_f32_16x16x16bf16_1k)
#define MFMA16x16(a, b, c) __builtin_amdgcn_mfma_f32_16x16x16bf16_1k(a, b, c, 0, 0, 0)
#elif __has_builtin(__builtin_amdgcn_mfma_f32_16x16x16_bf16)
#define MFMA16x16(a, b, c) __builtin_amdgcn_mfma_f32_16x16x16_bf16(a, b, c, 0, 0, 0)
#else
__device__ inline f32x4 mfma16_asm(bf16x4 a, bf16x4 b, f32x4 c) {
    f32x4 d;
    asm volatile("v_mfma_f32_16x16x16_bf16 %0, %1, %2, %3"
                 : "=v"(d) : "v"(a), "v"(b), "v"(c));
    return d;
}
#define MFMA16x16(a, b, c) mfma16_asm(a, b, c)
#endif

__device__ inline void gload_lds16(const short* g, short* lds) {
    __builtin_amdgcn_global_load_lds(
        (const __attribute__((address_space(1))) void*)g,
        (__attribute__((address_space(3))) void*)lds, 16, 0, 0);
}

// ---------------- LayerNorm: one block per row (C=1024), fp32 in, bf16 out ----
__launch_bounds__(256)
__global__ void ln_kernel(const float* __restrict__ x,
                          const float* __restrict__ g,
                          const float* __restrict__ be,
                          short* __restrict__ out) {
    __shared__ float red[2][4];
    const int row = blockIdx.x;
    const float* xr = x + (size_t)row * CD;
    float s = 0.f, ss = 0.f;
    for (int c = threadIdx.x; c < CD; c += 256) {
        float v = xr[c];
        s += v; ss += v * v;
    }
    #pragma unroll
    for (int off = 32; off > 0; off >>= 1) {
        s  += __shfl_down(s,  off, 64);
        ss += __shfl_down(ss, off, 64);
    }
    int wid = threadIdx.x >> 6, lane = threadIdx.x & 63;
    if (lane == 0) { red[0][wid] = s; red[1][wid] = ss; }
    __syncthreads();
    float sum   = red[0][0] + red[0][1] + red[0][2] + red[0][3];
    float sumsq = red[1][0] + red[1][1] + red[1][2] + red[1][3];
    float mu   = sum * (1.f / CD);
    float var  = sumsq * (1.f / CD) - mu * mu;
    float rstd = rsqrtf(var + 1e-5f);
    short* orow = out + (size_t)row * CD;
    for (int c = threadIdx.x; c < CD; c += 256) {
        float v = xr[c];
        orow[c] = f2bf((v - mu) * rstd * g[c] + be[c]);
    }
}

// ------------- Fused weight prep: all 64x64 fp32->bf16 transpose tiles -------
// blocks 0..767: Wq/Wk/Wv (per-head CDxDH slices) -> wqt (3,H,DH,C)
// 768..1023: Wo (CDxCD); 1024..2047: W1 (CDx4CD); 2048..3071: W2 (4CDxCD)
__launch_bounds__(256)
__global__ void prep_weights(const float* __restrict__ Wq, const float* __restrict__ Wk,
                             const float* __restrict__ Wv, const float* __restrict__ Wo,
                             const float* __restrict__ W1, const float* __restrict__ W2,
                             short* __restrict__ wqt, short* __restrict__ wot,
                             short* __restrict__ w1t, short* __restrict__ w2t) {
    __shared__ float tt[64][65];
    const int id = blockIdx.x;
    const float* in; short* out; int R, Cc, r0, c0;
    if (id < 768) {
        int which = id >> 8, rem = id & 255, hh = rem >> 4, ry = rem & 15;
        in  = (which == 0 ? Wq : which == 1 ? Wk : Wv) + (size_t)hh * CD * DH;
        out = wqt + (size_t)which * CD * CD + (size_t)hh * DH * CD;
        R = CD; Cc = DH; r0 = ry * 64; c0 = 0;
    } else if (id < 1024) {
        int t = id - 768;  in = Wo; out = wot; R = CD;     Cc = CD;     r0 = (t >> 4) * 64; c0 = (t & 15) * 64;
    } else if (id < 2048) {
        int t = id - 1024; in = W1; out = w1t; R = CD;     Cc = 4 * CD; r0 = (t >> 6) * 64; c0 = (t & 63) * 64;
    } else {
        int t = id - 2048; in = W2; out = w2t; R = 4 * CD; Cc = CD;     r0 = (t >> 4) * 64; c0 = (t & 15) * 64;
    }
    const int tid = threadIdx.x;
    #pragma unroll
    for (int i = 0; i < 16; ++i) {
        int e = i * 256 + tid;
        tt[e >> 6][e & 63] = in[(size_t)(r0 + (e >> 6)) * Cc + c0 + (e & 63)];
    }
    __syncthreads();
    #pragma unroll
    for (int i = 0; i < 16; ++i) {
        int e = i * 256 + tid;
        out[(size_t)(c0 + (e >> 6)) * R + r0 + (e & 63)] = f2bf(tt[e & 63][e >> 6]);
    }
}

// ------------- V transpose: vbf (BT x C bf16) -> vtg[b][h][d][t] bf16 -------
__launch_bounds__(256)
__global__ void vtrans(const short* __restrict__ vin, short* __restrict__ vout) {
    __shared__ short t[64 * 65];
    const int tid = threadIdx.x;
    const int bh = blockIdx.y;
    const int t0 = blockIdx.x * 64;
    const int b = bh >> 4, h = bh & 15;
    const short* src = vin + (size_t)b * TD * CD + (size_t)h * DH;
    short* dst = vout + (size_t)bh * DH * TD;
    #pragma unroll
    for (int i = 0; i < 16; ++i) {
        int e = i * 256 + tid;
        t[(e >> 6) * 65 + (e & 63)] = src[(size_t)(t0 + (e >> 6)) * CD + (e & 63)];
    }
    __syncthreads();
    #pragma unroll
    for (int i = 0; i < 16; ++i) {
        int e = i * 256 + tid;
        int d = e >> 6, tt = e & 63;
        dst[(size_t)d * TD + t0 + tt] = t[tt * 65 + d];
    }
}

// ---------------- MFMA GEMM: C(128 x TN) = A(M x K) . Bt(N x K)^T, bf16 ------
// Triple-buffered LDS + counted vmcnt(4) + raw barriers; XOR-swizzled 16B
// slots (source k-chunk ^= (row>>1)&3, read ^= (l16>>1)&3) -> conflict-free
// ds_read_b128 with linear gload_lds dest.
// GR=2 (512 threads): in-block split-K. Two 4-wave groups compute the same
// 128xTN tile over K-halves with private LDS triple-buffers (groups stay in
// lockstep through shared barriers: identical iteration counts). Group 1
// dumps fp32 acc to LDS after the final barrier; group 0 adds + epilogue.
// Used for the 256-block (1 block/CU) MODE-1 GEMMs: doubles waves/SIMD.
// MODE 1: + bias + fp32 resid -> fp32 out
// MODE 2: + bias, relu -> bf16 out
// MODE 5: QKV merged: N=3072; seg=col>>10 -> outb + seg*BT*CD; seg0 scaled by
//         C^-0.5 * log2(e)  (attention uses exp2)
template <int MODE, int TN, int GR>
__launch_bounds__(GR * 256)
__global__ void gemm_mfma(const short* __restrict__ A,
                          const short* __restrict__ Bt,
                          const float* __restrict__ bias,
                          const float* __restrict__ resid,
                          float* __restrict__ outf,
                          short* __restrict__ outb,
                          int N, int K) {
    // per group: 3 buffers of (128 + TN) rows x 32 cols bf16
    __shared__ __align__(16) short smem[GR * 3 * (128 + TN) * 32];
    const int tid = threadIdx.x;
    const int kgrp = (GR == 2) ? (tid >> 8) : 0;
    const int tid256 = tid & 255;
    const int w4 = tid256 >> 6, lane = tid & 63;
    const int quad = lane >> 4, l16 = lane & 15;
    const int wr = w4 >> 1, wc = w4 & 1;
    const int m0 = blockIdx.y * 128, n0 = blockIdx.x * TN;
    const int NT = TN / 32;
    const int kbase = kgrp * (K / GR);

    short* grpBase = smem + (size_t)kgrp * 3 * (128 + TN) * 32;
#define AS(bi) (grpBase + (bi) * (128 + TN) * 32)
#define BS(bi) (AS(bi) + 128 * 32)

    f32x4 acc[4][NT] = {};

    auto STAGE = [&](int kt, int bi) {
        const int k0 = kbase + kt * 32;
        short* as = AS(bi);
        short* bs = BS(bi);
        #pragma unroll
        for (int i = 0; i < 2; ++i) {
            int s = i * 256 + tid256;
            int row = s >> 2, kc = (s & 3) ^ ((row >> 1) & 3);
            gload_lds16(A + (size_t)(m0 + row) * K + k0 + kc * 8,
                        &as[(i * 256 + w4 * 64) * 8]);
        }
        #pragma unroll
        for (int i = 0; i < TN / 64; ++i) {
            int s = i * 256 + tid256;
            int row = s >> 2, kc = (s & 3) ^ ((row >> 1) & 3);
            gload_lds16(Bt + (size_t)(n0 + row) * K + k0 + kc * 8,
                        &bs[(i * 256 + w4 * 64) * 8]);
        }
    };

    auto COMPUTE = [&](int bi) {
        const int xo = (quad ^ ((l16 >> 1) & 3)) * 8;
        const short* as = AS(bi);
        const short* bs = BS(bi);
        bf16x8 a[4], b[NT];
        #pragma unroll
        for (int mt = 0; mt < 4; ++mt)
            a[mt] = *(const bf16x8*)&as[(wr * 64 + mt * 16 + l16) * 32 + xo];
        #pragma unroll
        for (int nt = 0; nt < NT; ++nt)
            b[nt] = *(const bf16x8*)&bs[(wc * (TN / 2) + nt * 16 + l16) * 32 + xo];
        #pragma unroll
        for (int mt = 0; mt < 4; ++mt)
            #pragma unroll
            for (int nt = 0; nt < NT; ++nt)
                acc[mt][nt] = __builtin_amdgcn_mfma_f32_16x16x32_bf16(a[mt], b[nt], acc[mt][nt], 0, 0, 0);
    };

    const int nk = (K / GR) >> 5;
    // prologue: tiles 0,1 in flight (4 loads/lane each for TN=128)
    STAGE(0, 0);
    STAGE(1, 1);
    int bi = 0;
    for (int t = 0; t < nk - 1; ++t) {
        // counted wait: tile t's loads done; tile t+1's (youngest 4) may fly
        asm volatile("s_waitcnt vmcnt(4)" ::: "memory");
        __builtin_amdgcn_s_barrier();
        asm volatile("" ::: "memory");
        int bn = bi + 2 >= 3 ? bi - 1 : bi + 2;
        if (t + 2 < nk) STAGE(t + 2, bn);
        COMPUTE(bi);
        bi = bi + 1 >= 3 ? 0 : bi + 1;
    }
    asm volatile("s_waitcnt vmcnt(0)" ::: "memory");
    __builtin_amdgcn_s_barrier();
    asm volatile("" ::: "memory");
    COMPUTE(bi);

    if (GR == 2) {
        // cross-group reduction: group1 acc -> LDS (slice-major, conflict-free)
        float* red = (float*)smem;
        __syncthreads();   // staging LDS dead; safe to alias
        if (kgrp == 1) {
            #pragma unroll
            for (int mt = 0; mt < 4; ++mt)
                #pragma unroll
                for (int nt = 0; nt < NT; ++nt)
                    *(f32x4*)&red[((mt * NT + nt) * 256 + w4 * 64 + lane) * 4] = acc[mt][nt];
        }
        __syncthreads();
        if (kgrp == 1) return;
        #pragma unroll
        for (int mt = 0; mt < 4; ++mt)
            #pragma unroll
            for (int nt = 0; nt < NT; ++nt) {
                f32x4 p = *(const f32x4*)&red[((mt * NT + nt) * 256 + w4 * 64 + lane) * 4];
                acc[mt][nt] += p;
            }
    }

    const float qsc = (MODE == 5 && n0 < CD) ? 0.03125f * 1.44269504f : 1.0f;
    short* ob5 = (MODE == 5) ? outb + (size_t)(n0 >> 10) * BT * CD : nullptr;

    #pragma unroll
    for (int mt = 0; mt < 4; ++mt)
        #pragma unroll
        for (int nt = 0; nt < NT; ++nt)
            #pragma unroll
            for (int reg = 0; reg < 4; ++reg) {
                int row = m0 + wr * 64 + mt * 16 + quad * 4 + reg;
                int col = n0 + wc * (TN / 2) + nt * 16 + l16;
                float v = acc[mt][nt][reg];
                if (MODE == 1) { v += bias[col] + resid[(size_t)row * N + col];
                                 outf[(size_t)row * N + col] = v; }
                if (MODE == 2) { v = fmaxf(v + bias[col], 0.f);
                                 outb[(size_t)row * N + col] = f2bf(v); }
                if (MODE == 5) { ob5[(size_t)row * CD + (col & 1023)] = f2bf(v * qsc); }
            }
#undef AS
#undef BS
}

// ---------------- Flash attention, split-K, MFMA bf16, no-max softmax --------
//  * 2-tile-deep register prefetch; counted vmcnt derived by compiler.
//  * STR 68: conflict-free for all access patterns; LDS 34816 B.
//  * setprio(1) around the MFMA/exp2 compute cluster; raw v_exp_f32.
#define BQ   128
#define BK   64
#define STR  68

__launch_bounds__(256)
__global__ void attn_mfma(const short* __restrict__ q,
                          const short* __restrict__ k,
                          const short* __restrict__ vt,
                          short* __restrict__ opart,
                          float* __restrict__ lpart) {
    __shared__ short Ks[2][BK * STR];
    __shared__ short Vt[2][DH * STR];

    const int tid  = threadIdx.x;
    const int w = tid >> 6, lane = tid & 63;
    const int quad = lane >> 4, l16 = lane & 15;
    const int h = blockIdx.y;
    const int b = blockIdx.z >> 1, split = blockIdx.z & 1;
    const int q0 = blockIdx.x * BQ;
    const size_t base  = (size_t)b * TD * CD + (size_t)h * DH;
    const size_t vbase = (size_t)(b * NH + h) * DH * TD;

    // Q frags (N-side of S^T mfma): lane holds Q[q=l16][d=quad*8+j]
    bf16x8 qf[2][2];
    #pragma unroll
    for (int rt = 0; rt < 2; ++rt) {
        const short* qp = q + base + (size_t)(q0 + w * 32 + rt * 16 + l16) * CD;
        qf[rt][0] = *(const bf16x8*)&qp[quad * 8];
        qf[rt][1] = *(const bf16x8*)&qp[32 + quad * 8];
    }

    float l_p[2] = {};   // per-lane: q = q0+w*32+rt*16+l16, keys quad*4+reg
    f32x4 O[2][4] = {};

    const int kbeg = split * (TD / 2);
    const int NTI = (TD / 2) / BK;   // 16, even

    // per-lane staging coords: rows r8 / r8+32, cols c8..c8+7
    const int r8 = tid >> 3, c8 = (tid & 7) * 8;
    const short* kg = k + base + c8;                       // + (kt+row)*CD
    const short* vg = vt + vbase + (size_t)r8 * TD + c8;   // + kt (+32*TD)

#define ISSUE_T(t, K0, K1, V0, V1) do {                                   \
        const size_t ko_ = (size_t)(kbeg + (t) * BK);                     \
        K0 = *(const bf16x8*)&kg[(ko_ + r8) * CD];                        \
        K1 = *(const bf16x8*)&kg[(ko_ + r8 + 32) * CD];                   \
        V0 = *(const bf16x8*)&vg[ko_];                                    \
        V1 = *(const bf16x8*)&vg[(size_t)32 * TD + ko_];                  \
    } while (0)

#define WRITE_T(buf, K0, K1, V0, V1) do {                                 \
        *(bf16x8*)&Ks[buf][r8 * STR + c8] = K0;                           \
        *(bf16x8*)&Ks[buf][(r8 + 32) * STR + c8] = K1;                    \
        *(bf16x8*)&Vt[buf][r8 * STR + c8] = V0;                           \
        *(bf16x8*)&Vt[buf][(r8 + 32) * STR + c8] = V1;                    \
    } while (0)

#define COMPUTE_T(buf) do {                                               \
        __builtin_amdgcn_s_setprio(1);                                    \
        _Pragma("unroll")                                                 \
        for (int ct = 0; ct < 4; ++ct) {                                  \
            bf16x8 kb0 = *(const bf16x8*)&Ks[buf][(ct * 16 + l16) * STR + quad * 8]; \
            bf16x8 kb1 = *(const bf16x8*)&Ks[buf][(ct * 16 + l16) * STR + 32 + quad * 8]; \
            bf16x4 pa[2];                                                 \
            _Pragma("unroll")                                             \
            for (int rt = 0; rt < 2; ++rt) {                              \
                f32x4 acc = (f32x4){0.f, 0.f, 0.f, 0.f};                  \
                acc = __builtin_amdgcn_mfma_f32_16x16x32_bf16(kb0, qf[rt][0], acc, 0, 0, 0); \
                acc = __builtin_amdgcn_mfma_f32_16x16x32_bf16(kb1, qf[rt][1], acc, 0, 0, 0); \
                float p0 = EXP2(acc[0]), p1 = EXP2(acc[1]);               \
                float p2 = EXP2(acc[2]), p3 = EXP2(acc[3]);               \
                l_p[rt] += (p0 + p1) + (p2 + p3);                         \
                union { u32x2 u; bf16x4 s; } cv_;                         \
                cv_.u = (u32x2){pk2bf(p0, p1), pk2bf(p2, p3)};            \
                pa[rt] = cv_.s;                                           \
            }                                                             \
            _Pragma("unroll")                                             \
            for (int dt = 0; dt < 4; ++dt) {                              \
                bf16x4 vb = *(const bf16x4*)&Vt[buf][(dt * 16 + l16) * STR + ct * 16 + quad * 4]; \
                O[0][dt] = MFMA16x16(pa[0], vb, O[0][dt]);                \
                O[1][dt] = MFMA16x16(pa[1], vb, O[1][dt]);                \
            }                                                             \
        }                                                                 \
        __builtin_amdgcn_s_setprio(0);                                    \
    } while (0)

    bf16x8 kA0, kA1, vA0, vA1;   // set A: odd tiles
    bf16x8 kB0, kB1, vB0, vB1;   // set B: even tiles

    // prologue: tile 0 direct to LDS[0] (one exposed latency), tile 1 -> A
    ISSUE_T(0, kA0, kA1, vA0, vA1);
    WRITE_T(0, kA0, kA1, vA0, vA1);
    ISSUE_T(1, kA0, kA1, vA0, vA1);
    __syncthreads();

    for (int it = 0; it < NTI; it += 2) {
        // tile it (LDS[0]); A holds tile it+1
        if (it + 2 < NTI) ISSUE_T(it + 2, kB0, kB1, vB0, vB1);
        COMPUTE_T(0);
        WRITE_T(1, kA0, kA1, vA0, vA1);
        __syncthreads();
        // tile it+1 (LDS[1]); B holds tile it+2
        if (it + 3 < NTI) ISSUE_T(it + 3, kA0, kA1, vA0, vA1);
        COMPUTE_T(1);
        if (it + 2 < NTI) WRITE_T(0, kB0, kB1, vB0, vB1);
        __syncthreads();
    }
#undef ISSUE_T
#undef WRITE_T
#undef COMPUTE_T

    // epilogue: unnormalized O (bf16) + l (fp32) per split
    short* osp = opart + (size_t)split * BT * CD;
    float* lsp = lpart + (size_t)split * BB * NH * TD + (size_t)(b * NH + h) * TD;
    #pragma unroll
    for (int rt = 0; rt < 2; ++rt) {
        float l = l_p[rt];
        l += __shfl_xor(l, 16, 64);
        l += __shfl_xor(l, 32, 64);
        if (lane < 16) lsp[q0 + w * 32 + rt * 16 + lane] = l;
        #pragma unroll
        for (int reg = 0; reg < 4; ++reg) {
            int row = q0 + w * 32 + rt * 16 + quad * 4 + reg;
            short* op = osp + base + (size_t)row * CD;
            #pragma unroll
            for (int dt = 0; dt < 4; ++dt)
                op[dt * 16 + l16] = f2bf(O[rt][dt][reg]);
        }
    }
}

// ---------------- Combine split-K partials: ob = (O0+O1)/(l0+l1), bf16 -------
__launch_bounds__(256)
__global__ void attn_combine(const short* __restrict__ opart,
                             const float* __restrict__ lpart,
                             short* __restrict__ ob) {
    const size_t idx = ((size_t)blockIdx.x * 256 + threadIdx.x) * 8;
    const int row = (int)(idx >> 10);        // / CD
    const int col = (int)(idx & 1023);
    const int b = row >> 11, qq = row & (TD - 1), hh = col >> 6;
    const size_t lbase = (size_t)(b * NH + hh) * TD + qq;
    const float l0 = lpart[lbase];
    const float l1 = lpart[(size_t)BB * NH * TD + lbase];
    const float inv = 1.f / (l0 + l1);
    bf16x8 a = *(const bf16x8*)&opart[idx];
    bf16x8 c = *(const bf16x8*)&opart[(size_t)BT * CD + idx];
    bf16x8 r;
    #pragma unroll
    for (int j = 0; j < 8; ++j)
        r[j] = f2bf((bf2f(a[j]) + bf2f(c[j])) * inv);
    *(bf16x8*)&ob[idx] = r;
}

extern "C" void kernel_launch(void* const* d_in, const int* in_sizes, int n_in,
                              void* d_out, int out_size, void* d_ws, size_t ws_size,
                              hipStream_t stream) {
    const float* x   = (const float*)d_in[0];
    const float* Wq  = (const float*)d_in[1];
    const float* Wk  = (const float*)d_in[2];
    const float* Wv  = (const float*)d_in[3];
    const float* Wo  = (const float*)d_in[4];
    const float* bo  = (const float*)d_in[5];
    const float* W1  = (const float*)d_in[6];
    const float* b1  = (const float*)d_in[7];
    const float* W2  = (const float*)d_in[8];
    const float* b2  = (const float*)d_in[9];
    const float* g1  = (const float*)d_in[10];
    const float* be1 = (const float*)d_in[11];
    const float* g2  = (const float*)d_in[12];
    const float* be2 = (const float*)d_in[13];
    float* out = (float*)d_out;

    const size_t SZ = (size_t)BT * CD;  // 4M elements
    float* ws  = (float*)d_ws;
    short* qbf = (short*)ws;                       // [0,1.5SZ): q|k|v bf16
    short* kbf = qbf + SZ;
    short* vbf = qbf + 2 * SZ;
    float* lpart = ws + SZ + SZ / 2;               // [1.5SZ,+128K floats)
    short* opart = (short*)(ws + 2 * SZ);          // [2SZ,3SZ): 2 x SZ bf16
    float* x1  = ws + 2 * SZ;                      // [2SZ,3SZ): after combine
    short* h   = (short*)(ws + 3 * SZ);            // [3SZ,3.5SZ)
    short* ob  = (short*)(ws + 3 * SZ + SZ / 2);   // [3.5SZ,4SZ)
    short* wqt = (short*)(ws + 4 * SZ);            // [4SZ,4.5SZ): 3xCD*CD + CD*CD
    short* wot = wqt + 3 * CD * CD;
    short* w1t = (short*)(ws + 4 * SZ + SZ / 2);   // [4.5SZ,5SZ)
    short* w2t = (short*)(ws + 5 * SZ);            // [5SZ,5.5SZ)
    short* vtg = (short*)(ws + 5 * SZ + SZ / 2);   // [5.5SZ,6SZ): V^T global
    short* ff1 = (short*)ws;                       // [0,2SZ): reuses dead q/k/v

    // 1) h1 = LN(x)  (bf16)
    ln_kernel<<<BT, 256, 0, stream>>>(x, g1, be1, h);

    // 2) all weight transposes fused (bf16 B^T layouts)
    prep_weights<<<3072, 256, 0, stream>>>(Wq, Wk, Wv, Wo, W1, W2, wqt, wot, w1t, w2t);

    // 3) merged q|k|v = h1 @ [Wq|Wk|Wv]  (bf16; C^-0.5*log2e folded into q)
    gemm_mfma<5, 128, 1><<<dim3(24, 32), 256, 0, stream>>>(h, wqt, nullptr, nullptr, nullptr, qbf, 3 * CD, CD);

    // 4) vtg = V^T per (b,h)
    vtrans<<<dim3(TD / 64, 2 * NH), 256, 0, stream>>>(vbf, vtg);

    // 5) attention split-K -> opart, lpart
    attn_mfma<<<dim3(TD / BQ, NH, BB * 2), 256, 0, stream>>>(qbf, kbf, vtg, opart, lpart);

    // 6) combine -> ob (bf16, concat-head layout)
    attn_combine<<<dim3((int)(SZ / (256 * 8))), 256, 0, stream>>>(opart, lpart, ob);

    // 7) x1 = ob @ Wo + bo + x  (fp32; 512-thr in-block split-K: 8 waves/CU)
    gemm_mfma<1, 128, 2><<<dim3(8, 32), 512, 0, stream>>>(ob, wot, bo, x, x1, nullptr, CD, CD);

    // 8) h2 = LN(x1)  (bf16)
    ln_kernel<<<BT, 256, 0, stream>>>(x1, g2, be2, h);

    // 9) ff1 = relu(h2 @ W1 + b1)  (bf16, N=4096)
    gemm_mfma<2, 128, 1><<<dim3(32, 32), 256, 0, stream>>>(h, w1t, b1, nullptr, nullptr, ff1, 4 * CD, CD);

    // 10) out = ff1 @ W2 + b2 + x1  (fp32, K=4096, in-block split-K)
    gemm_mfma<1, 128, 2><<<dim3(8, 32), 512, 0, stream>>>(ff1, w2t, b2, x1, out, nullptr, CD, 4 * CD);
}

// Round 5
// 328.784 us; speedup vs baseline: 1.3644x; 1.0367x over previous
//
#include <hip/hip_runtime.h>
#include <hip/hip_bf16.h>

#define BT   4096   // B*T
#define CD   1024   // C
#define TD   2048   // T
#define NH   16     // heads
#define DH   64     // head dim
#define BB   2      // batch

typedef __attribute__((ext_vector_type(8))) short bf16x8;
typedef __attribute__((ext_vector_type(4))) short bf16x4;
typedef __attribute__((ext_vector_type(4))) float f32x4;
typedef __attribute__((ext_vector_type(2))) unsigned int u32x2;

__device__ inline short f2bf(float f) {
    union { float fv; unsigned u; } x; x.fv = f;
    unsigned r = x.u + 0x7fffu + ((x.u >> 16) & 1u);
    return (short)(r >> 16);
}
__device__ inline float bf2f(short s) {
    union { unsigned u; float f; } x; x.u = ((unsigned)(unsigned short)s) << 16;
    return x.f;
}
__device__ inline unsigned pk2bf(float a, float b) {
    union { __hip_bfloat162 h; unsigned u; } cv;
    cv.h = __float22bfloat162_rn(float2{a, b});
    return cv.u;
}

// raw v_exp_f32 (2^x): avoid any OCML guard sequence
#if __has_builtin(__builtin_amdgcn_exp2f)
#define EXP2(x) __builtin_amdgcn_exp2f(x)
#else
#define EXP2(x) exp2f(x)
#endif

// K=16 bf16 MFMA: A-frag layout (lane: m=l16, k=quad*4+j) is bit-identical to
// the 16x16 C-layout (m=quad*4+reg, n=l16) of the swapped S^T MFMA -> P stays
// in registers for PV (no LDS round-trip).
#if __has_builtin(__builtin_amdgcn_mfma_f32_16x16x16bf16_1k)
#define MFMA16x16(a, b, c) __builtin_amdgcn_mfma_f32_16x16x16bf16_1k(a, b, c, 0, 0, 0)
#elif __has_builtin(__builtin_amdgcn_mfma_f32_16x16x16_bf16)
#define MFMA16x16(a, b, c) __builtin_amdgcn_mfma_f32_16x16x16_bf16(a, b, c, 0, 0, 0)
#else
__device__ inline f32x4 mfma16_asm(bf16x4 a, bf16x4 b, f32x4 c) {
    f32x4 d;
    asm volatile("v_mfma_f32_16x16x16_bf16 %0, %1, %2, %3"
                 : "=v"(d) : "v"(a), "v"(b), "v"(c));
    return d;
}
#define MFMA16x16(a, b, c) mfma16_asm(a, b, c)
#endif

__device__ inline void gload_lds16(const short* g, short* lds) {
    __builtin_amdgcn_global_load_lds(
        (const __attribute__((address_space(1))) void*)g,
        (__attribute__((address_space(3))) void*)lds, 16, 0, 0);
}

// ---------------- LayerNorm: one block per row (C=1024), fp32 in, bf16 out ----
__launch_bounds__(256)
__global__ void ln_kernel(const float* __restrict__ x,
                          const float* __restrict__ g,
                          const float* __restrict__ be,
                          short* __restrict__ out) {
    __shared__ float red[2][4];
    const int row = blockIdx.x;
    const float* xr = x + (size_t)row * CD;
    float s = 0.f, ss = 0.f;
    for (int c = threadIdx.x; c < CD; c += 256) {
        float v = xr[c];
        s += v; ss += v * v;
    }
    #pragma unroll
    for (int off = 32; off > 0; off >>= 1) {
        s  += __shfl_down(s,  off, 64);
        ss += __shfl_down(ss, off, 64);
    }
    int wid = threadIdx.x >> 6, lane = threadIdx.x & 63;
    if (lane == 0) { red[0][wid] = s; red[1][wid] = ss; }
    __syncthreads();
    float sum   = red[0][0] + red[0][1] + red[0][2] + red[0][3];
    float sumsq = red[1][0] + red[1][1] + red[1][2] + red[1][3];
    float mu   = sum * (1.f / CD);
    float var  = sumsq * (1.f / CD) - mu * mu;
    float rstd = rsqrtf(var + 1e-5f);
    short* orow = out + (size_t)row * CD;
    for (int c = threadIdx.x; c < CD; c += 256) {
        float v = xr[c];
        orow[c] = f2bf((v - mu) * rstd * g[c] + be[c]);
    }
}

// ------------- Fused weight prep: all 64x64 fp32->bf16 transpose tiles -------
// blocks 0..767: Wq/Wk/Wv (per-head CDxDH slices) -> wqt (3,H,DH,C)
// 768..1023: Wo (CDxCD); 1024..2047: W1 (CDx4CD); 2048..3071: W2 (4CDxCD)
__launch_bounds__(256)
__global__ void prep_weights(const float* __restrict__ Wq, const float* __restrict__ Wk,
                             const float* __restrict__ Wv, const float* __restrict__ Wo,
                             const float* __restrict__ W1, const float* __restrict__ W2,
                             short* __restrict__ wqt, short* __restrict__ wot,
                             short* __restrict__ w1t, short* __restrict__ w2t) {
    __shared__ float tt[64][65];
    const int id = blockIdx.x;
    const float* in; short* out; int R, Cc, r0, c0;
    if (id < 768) {
        int which = id >> 8, rem = id & 255, hh = rem >> 4, ry = rem & 15;
        in  = (which == 0 ? Wq : which == 1 ? Wk : Wv) + (size_t)hh * CD * DH;
        out = wqt + (size_t)which * CD * CD + (size_t)hh * DH * CD;
        R = CD; Cc = DH; r0 = ry * 64; c0 = 0;
    } else if (id < 1024) {
        int t = id - 768;  in = Wo; out = wot; R = CD;     Cc = CD;     r0 = (t >> 4) * 64; c0 = (t & 15) * 64;
    } else if (id < 2048) {
        int t = id - 1024; in = W1; out = w1t; R = CD;     Cc = 4 * CD; r0 = (t >> 6) * 64; c0 = (t & 63) * 64;
    } else {
        int t = id - 2048; in = W2; out = w2t; R = 4 * CD; Cc = CD;     r0 = (t >> 4) * 64; c0 = (t & 15) * 64;
    }
    const int tid = threadIdx.x;
    #pragma unroll
    for (int i = 0; i < 16; ++i) {
        int e = i * 256 + tid;
        tt[e >> 6][e & 63] = in[(size_t)(r0 + (e >> 6)) * Cc + c0 + (e & 63)];
    }
    __syncthreads();
    #pragma unroll
    for (int i = 0; i < 16; ++i) {
        int e = i * 256 + tid;
        out[(size_t)(c0 + (e >> 6)) * R + r0 + (e & 63)] = f2bf(tt[e & 63][e >> 6]);
    }
}

// ------------- V transpose: vbf (BT x C bf16) -> vtg[b][h][d][t] bf16 -------
__launch_bounds__(256)
__global__ void vtrans(const short* __restrict__ vin, short* __restrict__ vout) {
    __shared__ short t[64 * 65];
    const int tid = threadIdx.x;
    const int bh = blockIdx.y;
    const int t0 = blockIdx.x * 64;
    const int b = bh >> 4, h = bh & 15;
    const short* src = vin + (size_t)b * TD * CD + (size_t)h * DH;
    short* dst = vout + (size_t)bh * DH * TD;
    #pragma unroll
    for (int i = 0; i < 16; ++i) {
        int e = i * 256 + tid;
        t[(e >> 6) * 65 + (e & 63)] = src[(size_t)(t0 + (e >> 6)) * CD + (e & 63)];
    }
    __syncthreads();
    #pragma unroll
    for (int i = 0; i < 16; ++i) {
        int e = i * 256 + tid;
        int d = e >> 6, tt = e & 63;
        dst[(size_t)d * TD + t0 + tt] = t[tt * 65 + d];
    }
}

// ---------------- MFMA GEMM: C(128 x TN) = A(M x K) . Bt(N x K)^T, bf16 ------
// Triple-buffered LDS + counted vmcnt(4) + raw barriers; XOR-swizzled 16B
// slots -> conflict-free ds_read_b128 with linear gload_lds dest.
// GR=2 (512 threads): in-block split-K (two 4-wave groups, private LDS
// triple-buffers, lockstep barriers; group1 reduces via LDS at the end).
// R13: XCD-aware tile swizzle. HW assigns block i -> XCD i%8. Map so XCD k
// owns m-tiles [4k,4k+4) x ALL n-tiles: the blocks sharing an A-row-panel
// sit on one XCD and stream the same A bytes in-phase -> A-panel becomes an
// L2 hit instead of an 8-32x LLC/HBM re-read (A re-read was ~256MB of FF2's
// ~296MB L2-miss traffic). B stays L2-shared per XCD (8MB). Requires
// gridDim.y==32 (all our GEMMs) -> mt = (li&7)*4 + ((li>>3)&3), nt = li>>5.
// MODE 1: + bias + fp32 resid -> fp32 out
// MODE 2: + bias, relu -> bf16 out
// MODE 5: QKV merged: N=3072; seg=col>>10 -> outb + seg*BT*CD; seg0 scaled by
//         C^-0.5 * log2(e)  (attention uses exp2)
template <int MODE, int TN, int GR>
__launch_bounds__(GR * 256)
__global__ void gemm_mfma(const short* __restrict__ A,
                          const short* __restrict__ Bt,
                          const float* __restrict__ bias,
                          const float* __restrict__ resid,
                          float* __restrict__ outf,
                          short* __restrict__ outb,
                          int N, int K) {
    // per group: 3 buffers of (128 + TN) rows x 32 cols bf16
    __shared__ __align__(16) short smem[GR * 3 * (128 + TN) * 32];
    const int tid = threadIdx.x;
    const int kgrp = (GR == 2) ? (tid >> 8) : 0;
    const int tid256 = tid & 255;
    const int w4 = tid256 >> 6, lane = tid & 63;
    const int quad = lane >> 4, l16 = lane & 15;
    const int wr = w4 >> 1, wc = w4 & 1;
    // XCD-aware swizzle: li -> (m-tile, n-tile); XCD k = li&7 owns m 4k..4k+4
    const int li = blockIdx.y * gridDim.x + blockIdx.x;
    const int m0 = ((li & 7) * 4 + ((li >> 3) & 3)) * 128;
    const int n0 = (li >> 5) * TN;
    const int NT = TN / 32;
    const int kbase = kgrp * (K / GR);

    short* grpBase = smem + (size_t)kgrp * 3 * (128 + TN) * 32;
#define AS(bi) (grpBase + (bi) * (128 + TN) * 32)
#define BS(bi) (AS(bi) + 128 * 32)

    f32x4 acc[4][NT] = {};

    auto STAGE = [&](int kt, int bi) {
        const int k0 = kbase + kt * 32;
        short* as = AS(bi);
        short* bs = BS(bi);
        #pragma unroll
        for (int i = 0; i < 2; ++i) {
            int s = i * 256 + tid256;
            int row = s >> 2, kc = (s & 3) ^ ((row >> 1) & 3);
            gload_lds16(A + (size_t)(m0 + row) * K + k0 + kc * 8,
                        &as[(i * 256 + w4 * 64) * 8]);
        }
        #pragma unroll
        for (int i = 0; i < TN / 64; ++i) {
            int s = i * 256 + tid256;
            int row = s >> 2, kc = (s & 3) ^ ((row >> 1) & 3);
            gload_lds16(Bt + (size_t)(n0 + row) * K + k0 + kc * 8,
                        &bs[(i * 256 + w4 * 64) * 8]);
        }
    };

    auto COMPUTE = [&](int bi) {
        const int xo = (quad ^ ((l16 >> 1) & 3)) * 8;
        const short* as = AS(bi);
        const short* bs = BS(bi);
        bf16x8 a[4], b[NT];
        #pragma unroll
        for (int mt = 0; mt < 4; ++mt)
            a[mt] = *(const bf16x8*)&as[(wr * 64 + mt * 16 + l16) * 32 + xo];
        #pragma unroll
        for (int nt = 0; nt < NT; ++nt)
            b[nt] = *(const bf16x8*)&bs[(wc * (TN / 2) + nt * 16 + l16) * 32 + xo];
        #pragma unroll
        for (int mt = 0; mt < 4; ++mt)
            #pragma unroll
            for (int nt = 0; nt < NT; ++nt)
                acc[mt][nt] = __builtin_amdgcn_mfma_f32_16x16x32_bf16(a[mt], b[nt], acc[mt][nt], 0, 0, 0);
    };

    const int nk = (K / GR) >> 5;
    // prologue: tiles 0,1 in flight (4 loads/lane each for TN=128)
    STAGE(0, 0);
    STAGE(1, 1);
    int bi = 0;
    for (int t = 0; t < nk - 1; ++t) {
        // counted wait: tile t's loads done; tile t+1's (youngest 4) may fly
        asm volatile("s_waitcnt vmcnt(4)" ::: "memory");
        __builtin_amdgcn_s_barrier();
        asm volatile("" ::: "memory");
        int bn = bi + 2 >= 3 ? bi - 1 : bi + 2;
        if (t + 2 < nk) STAGE(t + 2, bn);
        COMPUTE(bi);
        bi = bi + 1 >= 3 ? 0 : bi + 1;
    }
    asm volatile("s_waitcnt vmcnt(0)" ::: "memory");
    __builtin_amdgcn_s_barrier();
    asm volatile("" ::: "memory");
    COMPUTE(bi);

    if (GR == 2) {
        // cross-group reduction: group1 acc -> LDS (slice-major, conflict-free)
        float* red = (float*)smem;
        __syncthreads();   // staging LDS dead; safe to alias
        if (kgrp == 1) {
            #pragma unroll
            for (int mt = 0; mt < 4; ++mt)
                #pragma unroll
                for (int nt = 0; nt < NT; ++nt)
                    *(f32x4*)&red[((mt * NT + nt) * 256 + w4 * 64 + lane) * 4] = acc[mt][nt];
        }
        __syncthreads();
        if (kgrp == 1) return;
        #pragma unroll
        for (int mt = 0; mt < 4; ++mt)
            #pragma unroll
            for (int nt = 0; nt < NT; ++nt) {
                f32x4 p = *(const f32x4*)&red[((mt * NT + nt) * 256 + w4 * 64 + lane) * 4];
                acc[mt][nt] += p;
            }
    }

    const float qsc = (MODE == 5 && n0 < CD) ? 0.03125f * 1.44269504f : 1.0f;
    short* ob5 = (MODE == 5) ? outb + (size_t)(n0 >> 10) * BT * CD : nullptr;

    #pragma unroll
    for (int mt = 0; mt < 4; ++mt)
        #pragma unroll
        for (int nt = 0; nt < NT; ++nt)
            #pragma unroll
            for (int reg = 0; reg < 4; ++reg) {
                int row = m0 + wr * 64 + mt * 16 + quad * 4 + reg;
                int col = n0 + wc * (TN / 2) + nt * 16 + l16;
                float v = acc[mt][nt][reg];
                if (MODE == 1) { v += bias[col] + resid[(size_t)row * N + col];
                                 outf[(size_t)row * N + col] = v; }
                if (MODE == 2) { v = fmaxf(v + bias[col], 0.f);
                                 outb[(size_t)row * N + col] = f2bf(v); }
                if (MODE == 5) { ob5[(size_t)row * CD + (col & 1023)] = f2bf(v * qsc); }
            }
#undef AS
#undef BS
}

// ---------------- Flash attention, split-K, MFMA bf16, no-max softmax --------
//  * 2-tile-deep register prefetch; counted vmcnt derived by compiler.
//  * STR 68: conflict-free for all access patterns; LDS 34816 B.
//  * setprio(1) around the MFMA/exp2 compute cluster; raw v_exp_f32.
#define BQ   128
#define BK   64
#define STR  68

__launch_bounds__(256)
__global__ void attn_mfma(const short* __restrict__ q,
                          const short* __restrict__ k,
                          const short* __restrict__ vt,
                          short* __restrict__ opart,
                          float* __restrict__ lpart) {
    __shared__ short Ks[2][BK * STR];
    __shared__ short Vt[2][DH * STR];

    const int tid  = threadIdx.x;
    const int w = tid >> 6, lane = tid & 63;
    const int quad = lane >> 4, l16 = lane & 15;
    const int h = blockIdx.y;
    const int b = blockIdx.z >> 1, split = blockIdx.z & 1;
    const int q0 = blockIdx.x * BQ;
    const size_t base  = (size_t)b * TD * CD + (size_t)h * DH;
    const size_t vbase = (size_t)(b * NH + h) * DH * TD;

    // Q frags (N-side of S^T mfma): lane holds Q[q=l16][d=quad*8+j]
    bf16x8 qf[2][2];
    #pragma unroll
    for (int rt = 0; rt < 2; ++rt) {
        const short* qp = q + base + (size_t)(q0 + w * 32 + rt * 16 + l16) * CD;
        qf[rt][0] = *(const bf16x8*)&qp[quad * 8];
        qf[rt][1] = *(const bf16x8*)&qp[32 + quad * 8];
    }

    float l_p[2] = {};   // per-lane: q = q0+w*32+rt*16+l16, keys quad*4+reg
    f32x4 O[2][4] = {};

    const int kbeg = split * (TD / 2);
    const int NTI = (TD / 2) / BK;   // 16, even

    // per-lane staging coords: rows r8 / r8+32, cols c8..c8+7
    const int r8 = tid >> 3, c8 = (tid & 7) * 8;
    const short* kg = k + base + c8;                       // + (kt+row)*CD
    const short* vg = vt + vbase + (size_t)r8 * TD + c8;   // + kt (+32*TD)

#define ISSUE_T(t, K0, K1, V0, V1) do {                                   \
        const size_t ko_ = (size_t)(kbeg + (t) * BK);                     \
        K0 = *(const bf16x8*)&kg[(ko_ + r8) * CD];                        \
        K1 = *(const bf16x8*)&kg[(ko_ + r8 + 32) * CD];                   \
        V0 = *(const bf16x8*)&vg[ko_];                                    \
        V1 = *(const bf16x8*)&vg[(size_t)32 * TD + ko_];                  \
    } while (0)

#define WRITE_T(buf, K0, K1, V0, V1) do {                                 \
        *(bf16x8*)&Ks[buf][r8 * STR + c8] = K0;                           \
        *(bf16x8*)&Ks[buf][(r8 + 32) * STR + c8] = K1;                    \
        *(bf16x8*)&Vt[buf][r8 * STR + c8] = V0;                           \
        *(bf16x8*)&Vt[buf][(r8 + 32) * STR + c8] = V1;                    \
    } while (0)

#define COMPUTE_T(buf) do {                                               \
        __builtin_amdgcn_s_setprio(1);                                    \
        _Pragma("unroll")                                                 \
        for (int ct = 0; ct < 4; ++ct) {                                  \
            bf16x8 kb0 = *(const bf16x8*)&Ks[buf][(ct * 16 + l16) * STR + quad * 8]; \
            bf16x8 kb1 = *(const bf16x8*)&Ks[buf][(ct * 16 + l16) * STR + 32 + quad * 8]; \
            bf16x4 pa[2];                                                 \
            _Pragma("unroll")                                             \
            for (int rt = 0; rt < 2; ++rt) {                              \
                f32x4 acc = (f32x4){0.f, 0.f, 0.f, 0.f};                  \
                acc = __builtin_amdgcn_mfma_f32_16x16x32_bf16(kb0, qf[rt][0], acc, 0, 0, 0); \
                acc = __builtin_amdgcn_mfma_f32_16x16x32_bf16(kb1, qf[rt][1], acc, 0, 0, 0); \
                float p0 = EXP2(acc[0]), p1 = EXP2(acc[1]);               \
                float p2 = EXP2(acc[2]), p3 = EXP2(acc[3]);               \
                l_p[rt] += (p0 + p1) + (p2 + p3);                         \
                union { u32x2 u; bf16x4 s; } cv_;                         \
                cv_.u = (u32x2){pk2bf(p0, p1), pk2bf(p2, p3)};            \
                pa[rt] = cv_.s;                                           \
            }                                                             \
            _Pragma("unroll")                                             \
            for (int dt = 0; dt < 4; ++dt) {                              \
                bf16x4 vb = *(const bf16x4*)&Vt[buf][(dt * 16 + l16) * STR + ct * 16 + quad * 4]; \
                O[0][dt] = MFMA16x16(pa[0], vb, O[0][dt]);                \
                O[1][dt] = MFMA16x16(pa[1], vb, O[1][dt]);                \
            }                                                             \
        }                                                                 \
        __builtin_amdgcn_s_setprio(0);                                    \
    } while (0)

    bf16x8 kA0, kA1, vA0, vA1;   // set A: odd tiles
    bf16x8 kB0, kB1, vB0, vB1;   // set B: even tiles

    // prologue: tile 0 direct to LDS[0] (one exposed latency), tile 1 -> A
    ISSUE_T(0, kA0, kA1, vA0, vA1);
    WRITE_T(0, kA0, kA1, vA0, vA1);
    ISSUE_T(1, kA0, kA1, vA0, vA1);
    __syncthreads();

    for (int it = 0; it < NTI; it += 2) {
        // tile it (LDS[0]); A holds tile it+1
        if (it + 2 < NTI) ISSUE_T(it + 2, kB0, kB1, vB0, vB1);
        COMPUTE_T(0);
        WRITE_T(1, kA0, kA1, vA0, vA1);
        __syncthreads();
        // tile it+1 (LDS[1]); B holds tile it+2
        if (it + 3 < NTI) ISSUE_T(it + 3, kA0, kA1, vA0, vA1);
        COMPUTE_T(1);
        if (it + 2 < NTI) WRITE_T(0, kB0, kB1, vB0, vB1);
        __syncthreads();
    }
#undef ISSUE_T
#undef WRITE_T
#undef COMPUTE_T

    // epilogue: unnormalized O (bf16) + l (fp32) per split
    short* osp = opart + (size_t)split * BT * CD;
    float* lsp = lpart + (size_t)split * BB * NH * TD + (size_t)(b * NH + h) * TD;
    #pragma unroll
    for (int rt = 0; rt < 2; ++rt) {
        float l = l_p[rt];
        l += __shfl_xor(l, 16, 64);
        l += __shfl_xor(l, 32, 64);
        if (lane < 16) lsp[q0 + w * 32 + rt * 16 + lane] = l;
        #pragma unroll
        for (int reg = 0; reg < 4; ++reg) {
            int row = q0 + w * 32 + rt * 16 + quad * 4 + reg;
            short* op = osp + base + (size_t)row * CD;
            #pragma unroll
            for (int dt = 0; dt < 4; ++dt)
                op[dt * 16 + l16] = f2bf(O[rt][dt][reg]);
        }
    }
}

// ---------------- Combine split-K partials: ob = (O0+O1)/(l0+l1), bf16 -------
__launch_bounds__(256)
__global__ void attn_combine(const short* __restrict__ opart,
                             const float* __restrict__ lpart,
                             short* __restrict__ ob) {
    const size_t idx = ((size_t)blockIdx.x * 256 + threadIdx.x) * 8;
    const int row = (int)(idx >> 10);        // / CD
    const int col = (int)(idx & 1023);
    const int b = row >> 11, qq = row & (TD - 1), hh = col >> 6;
    const size_t lbase = (size_t)(b * NH + hh) * TD + qq;
    const float l0 = lpart[lbase];
    const float l1 = lpart[(size_t)BB * NH * TD + lbase];
    const float inv = 1.f / (l0 + l1);
    bf16x8 a = *(const bf16x8*)&opart[idx];
    bf16x8 c = *(const bf16x8*)&opart[(size_t)BT * CD + idx];
    bf16x8 r;
    #pragma unroll
    for (int j = 0; j < 8; ++j)
        r[j] = f2bf((bf2f(a[j]) + bf2f(c[j])) * inv);
    *(bf16x8*)&ob[idx] = r;
}

extern "C" void kernel_launch(void* const* d_in, const int* in_sizes, int n_in,
                              void* d_out, int out_size, void* d_ws, size_t ws_size,
                              hipStream_t stream) {
    const float* x   = (const float*)d_in[0];
    const float* Wq  = (const float*)d_in[1];
    const float* Wk  = (const float*)d_in[2];
    const float* Wv  = (const float*)d_in[3];
    const float* Wo  = (const float*)d_in[4];
    const float* bo  = (const float*)d_in[5];
    const float* W1  = (const float*)d_in[6];
    const float* b1  = (const float*)d_in[7];
    const float* W2  = (const float*)d_in[8];
    const float* b2  = (const float*)d_in[9];
    const float* g1  = (const float*)d_in[10];
    const float* be1 = (const float*)d_in[11];
    const float* g2  = (const float*)d_in[12];
    const float* be2 = (const float*)d_in[13];
    float* out = (float*)d_out;

    const size_t SZ = (size_t)BT * CD;  // 4M elements
    float* ws  = (float*)d_ws;
    short* qbf = (short*)ws;                       // [0,1.5SZ): q|k|v bf16
    short* kbf = qbf + SZ;
    short* vbf = qbf + 2 * SZ;
    float* lpart = ws + SZ + SZ / 2;               // [1.5SZ,+128K floats)
    short* opart = (short*)(ws + 2 * SZ);          // [2SZ,3SZ): 2 x SZ bf16
    float* x1  = ws + 2 * SZ;                      // [2SZ,3SZ): after combine
    short* h   = (short*)(ws + 3 * SZ);            // [3SZ,3.5SZ)
    short* ob  = (short*)(ws + 3 * SZ + SZ / 2);   // [3.5SZ,4SZ)
    short* wqt = (short*)(ws + 4 * SZ);            // [4SZ,4.5SZ): 3xCD*CD + CD*CD
    short* wot = wqt + 3 * CD * CD;
    short* w1t = (short*)(ws + 4 * SZ + SZ / 2);   // [4.5SZ,5SZ)
    short* w2t = (short*)(ws + 5 * SZ);            // [5SZ,5.5SZ)
    short* vtg = (short*)(ws + 5 * SZ + SZ / 2);   // [5.5SZ,6SZ): V^T global
    short* ff1 = (short*)ws;                       // [0,2SZ): reuses dead q/k/v

    // 1) h1 = LN(x)  (bf16)
    ln_kernel<<<BT, 256, 0, stream>>>(x, g1, be1, h);

    // 2) all weight transposes fused (bf16 B^T layouts)
    prep_weights<<<3072, 256, 0, stream>>>(Wq, Wk, Wv, Wo, W1, W2, wqt, wot, w1t, w2t);

    // 3) merged q|k|v = h1 @ [Wq|Wk|Wv]  (bf16; C^-0.5*log2e folded into q)
    gemm_mfma<5, 128, 1><<<dim3(24, 32), 256, 0, stream>>>(h, wqt, nullptr, nullptr, nullptr, qbf, 3 * CD, CD);

    // 4) vtg = V^T per (b,h)
    vtrans<<<dim3(TD / 64, 2 * NH), 256, 0, stream>>>(vbf, vtg);

    // 5) attention split-K -> opart, lpart
    attn_mfma<<<dim3(TD / BQ, NH, BB * 2), 256, 0, stream>>>(qbf, kbf, vtg, opart, lpart);

    // 6) combine -> ob (bf16, concat-head layout)
    attn_combine<<<dim3((int)(SZ / (256 * 8))), 256, 0, stream>>>(opart, lpart, ob);

    // 7) x1 = ob @ Wo + bo + x  (fp32; 512-thr in-block split-K)
    gemm_mfma<1, 128, 2><<<dim3(8, 32), 512, 0, stream>>>(ob, wot, bo, x, x1, nullptr, CD, CD);

    // 8) h2 = LN(x1)  (bf16)
    ln_kernel<<<BT, 256, 0, stream>>>(x1, g2, be2, h);

    // 9) ff1 = relu(h2 @ W1 + b1)  (bf16, N=4096)
    gemm_mfma<2, 128, 1><<<dim3(32, 32), 256, 0, stream>>>(h, w1t, b1, nullptr, nullptr, ff1, 4 * CD, CD);

    // 10) out = ff1 @ W2 + b2 + x1  (fp32, K=4096, in-block split-K)
    gemm_mfma<1, 128, 2><<<dim3(8, 32), 512, 0, stream>>>(ff1, w2t, b2, x1, out, nullptr, CD, 4 * CD);
}

// Round 6
// 324.027 us; speedup vs baseline: 1.3844x; 1.0147x over previous
//
#include <hip/hip_runtime.h>
#include <hip/hip_bf16.h>

#define BT   4096   // B*T
#define CD   1024   // C
#define TD   2048   // T
#define NH   16     // heads
#define DH   64     // head dim
#define BB   2      // batch

typedef __attribute__((ext_vector_type(8))) short bf16x8;
typedef __attribute__((ext_vector_type(4))) short bf16x4;
typedef __attribute__((ext_vector_type(4))) float f32x4;
typedef __attribute__((ext_vector_type(2))) unsigned int u32x2;
typedef __attribute__((ext_vector_type(4))) unsigned int u32x4;

__device__ inline short f2bf(float f) {
    union { float fv; unsigned u; } x; x.fv = f;
    unsigned r = x.u + 0x7fffu + ((x.u >> 16) & 1u);
    return (short)(r >> 16);
}
__device__ inline float bf2f(short s) {
    union { unsigned u; float f; } x; x.u = ((unsigned)(unsigned short)s) << 16;
    return x.f;
}
__device__ inline unsigned pk2bf(float a, float b) {
    union { __hip_bfloat162 h; unsigned u; } cv;
    cv.h = __float22bfloat162_rn(float2{a, b});
    return cv.u;
}

// raw v_exp_f32 (2^x): avoid any OCML guard sequence
#if __has_builtin(__builtin_amdgcn_exp2f)
#define EXP2(x) __builtin_amdgcn_exp2f(x)
#else
#define EXP2(x) exp2f(x)
#endif

__device__ inline void gload_lds16(const short* g, short* lds) {
    __builtin_amdgcn_global_load_lds(
        (const __attribute__((address_space(1))) void*)g,
        (__attribute__((address_space(3))) void*)lds, 16, 0, 0);
}

// ---------------- LayerNorm: one block per row (C=1024), fp32 in, bf16 out ----
__launch_bounds__(256)
__global__ void ln_kernel(const float* __restrict__ x,
                          const float* __restrict__ g,
                          const float* __restrict__ be,
                          short* __restrict__ out) {
    __shared__ float red[2][4];
    const int row = blockIdx.x;
    const float* xr = x + (size_t)row * CD;
    float s = 0.f, ss = 0.f;
    for (int c = threadIdx.x; c < CD; c += 256) {
        float v = xr[c];
        s += v; ss += v * v;
    }
    #pragma unroll
    for (int off = 32; off > 0; off >>= 1) {
        s  += __shfl_down(s,  off, 64);
        ss += __shfl_down(ss, off, 64);
    }
    int wid = threadIdx.x >> 6, lane = threadIdx.x & 63;
    if (lane == 0) { red[0][wid] = s; red[1][wid] = ss; }
    __syncthreads();
    float sum   = red[0][0] + red[0][1] + red[0][2] + red[0][3];
    float sumsq = red[1][0] + red[1][1] + red[1][2] + red[1][3];
    float mu   = sum * (1.f / CD);
    float var  = sumsq * (1.f / CD) - mu * mu;
    float rstd = rsqrtf(var + 1e-5f);
    short* orow = out + (size_t)row * CD;
    for (int c = threadIdx.x; c < CD; c += 256) {
        float v = xr[c];
        orow[c] = f2bf((v - mu) * rstd * g[c] + be[c]);
    }
}

// ------------- Fused weight prep: all 64x64 fp32->bf16 transpose tiles -------
// blocks 0..767: Wq/Wk/Wv (per-head CDxDH slices) -> wqt (3,H,DH,C)
// 768..1023: Wo (CDxCD); 1024..2047: W1 (CDx4CD); 2048..3071: W2 (4CDxCD)
__launch_bounds__(256)
__global__ void prep_weights(const float* __restrict__ Wq, const float* __restrict__ Wk,
                             const float* __restrict__ Wv, const float* __restrict__ Wo,
                             const float* __restrict__ W1, const float* __restrict__ W2,
                             short* __restrict__ wqt, short* __restrict__ wot,
                             short* __restrict__ w1t, short* __restrict__ w2t) {
    __shared__ float tt[64][65];
    const int id = blockIdx.x;
    const float* in; short* out; int R, Cc, r0, c0;
    if (id < 768) {
        int which = id >> 8, rem = id & 255, hh = rem >> 4, ry = rem & 15;
        in  = (which == 0 ? Wq : which == 1 ? Wk : Wv) + (size_t)hh * CD * DH;
        out = wqt + (size_t)which * CD * CD + (size_t)hh * DH * CD;
        R = CD; Cc = DH; r0 = ry * 64; c0 = 0;
    } else if (id < 1024) {
        int t = id - 768;  in = Wo; out = wot; R = CD;     Cc = CD;     r0 = (t >> 4) * 64; c0 = (t & 15) * 64;
    } else if (id < 2048) {
        int t = id - 1024; in = W1; out = w1t; R = CD;     Cc = 4 * CD; r0 = (t >> 6) * 64; c0 = (t & 63) * 64;
    } else {
        int t = id - 2048; in = W2; out = w2t; R = 4 * CD; Cc = CD;     r0 = (t >> 4) * 64; c0 = (t & 15) * 64;
    }
    const int tid = threadIdx.x;
    #pragma unroll
    for (int i = 0; i < 16; ++i) {
        int e = i * 256 + tid;
        tt[e >> 6][e & 63] = in[(size_t)(r0 + (e >> 6)) * Cc + c0 + (e & 63)];
    }
    __syncthreads();
    #pragma unroll
    for (int i = 0; i < 16; ++i) {
        int e = i * 256 + tid;
        out[(size_t)(c0 + (e >> 6)) * R + r0 + (e & 63)] = f2bf(tt[e & 63][e >> 6]);
    }
}

// ------------- V transpose: vbf (BT x C bf16) -> vtg[b][h][d][t] bf16 -------
__launch_bounds__(256)
__global__ void vtrans(const short* __restrict__ vin, short* __restrict__ vout) {
    __shared__ short t[64 * 65];
    const int tid = threadIdx.x;
    const int bh = blockIdx.y;
    const int t0 = blockIdx.x * 64;
    const int b = bh >> 4, h = bh & 15;
    const short* src = vin + (size_t)b * TD * CD + (size_t)h * DH;
    short* dst = vout + (size_t)bh * DH * TD;
    #pragma unroll
    for (int i = 0; i < 16; ++i) {
        int e = i * 256 + tid;
        t[(e >> 6) * 65 + (e & 63)] = src[(size_t)(t0 + (e >> 6)) * CD + (e & 63)];
    }
    __syncthreads();
    #pragma unroll
    for (int i = 0; i < 16; ++i) {
        int e = i * 256 + tid;
        int d = e >> 6, tt = e & 63;
        dst[(size_t)d * TD + t0 + tt] = t[tt * 65 + d];
    }
}

// ---------------- MFMA GEMM: C(128 x TN) = A(M x K) . Bt(N x K)^T, bf16 ------
// Triple-buffered LDS + counted vmcnt(4) + raw barriers; XOR-swizzled 16B
// slots -> conflict-free ds_read_b128 with linear gload_lds dest.
// GR=2 (512 threads): in-block split-K (two 4-wave groups, private LDS
// triple-buffers, lockstep barriers; group1 reduces via LDS at the end).
// XCD-aware tile swizzle: XCD k = li&7 owns m-tiles [4k,4k+4) x all n-tiles
// -> A-row-panel is L2-local per XCD instead of an 8-32x LLC/HBM re-read.
// MODE 1: + bias + fp32 resid -> fp32 out
// MODE 2: + bias, relu -> bf16 out
// MODE 5: QKV merged: N=3072; seg=col>>10 -> outb + seg*BT*CD; seg0 scaled by
//         C^-0.5 * log2(e)  (attention uses exp2)
template <int MODE, int TN, int GR>
__launch_bounds__(GR * 256)
__global__ void gemm_mfma(const short* __restrict__ A,
                          const short* __restrict__ Bt,
                          const float* __restrict__ bias,
                          const float* __restrict__ resid,
                          float* __restrict__ outf,
                          short* __restrict__ outb,
                          int N, int K) {
    // per group: 3 buffers of (128 + TN) rows x 32 cols bf16
    __shared__ __align__(16) short smem[GR * 3 * (128 + TN) * 32];
    const int tid = threadIdx.x;
    const int kgrp = (GR == 2) ? (tid >> 8) : 0;
    const int tid256 = tid & 255;
    const int w4 = tid256 >> 6, lane = tid & 63;
    const int quad = lane >> 4, l16 = lane & 15;
    const int wr = w4 >> 1, wc = w4 & 1;
    // XCD-aware swizzle: li -> (m-tile, n-tile); XCD k = li&7 owns m 4k..4k+4
    const int li = blockIdx.y * gridDim.x + blockIdx.x;
    const int m0 = ((li & 7) * 4 + ((li >> 3) & 3)) * 128;
    const int n0 = (li >> 5) * TN;
    const int NT = TN / 32;
    const int kbase = kgrp * (K / GR);

    short* grpBase = smem + (size_t)kgrp * 3 * (128 + TN) * 32;
#define AS(bi) (grpBase + (bi) * (128 + TN) * 32)
#define BS(bi) (AS(bi) + 128 * 32)

    f32x4 acc[4][NT] = {};

    auto STAGE = [&](int kt, int bi) {
        const int k0 = kbase + kt * 32;
        short* as = AS(bi);
        short* bs = BS(bi);
        #pragma unroll
        for (int i = 0; i < 2; ++i) {
            int s = i * 256 + tid256;
            int row = s >> 2, kc = (s & 3) ^ ((row >> 1) & 3);
            gload_lds16(A + (size_t)(m0 + row) * K + k0 + kc * 8,
                        &as[(i * 256 + w4 * 64) * 8]);
        }
        #pragma unroll
        for (int i = 0; i < TN / 64; ++i) {
            int s = i * 256 + tid256;
            int row = s >> 2, kc = (s & 3) ^ ((row >> 1) & 3);
            gload_lds16(Bt + (size_t)(n0 + row) * K + k0 + kc * 8,
                        &bs[(i * 256 + w4 * 64) * 8]);
        }
    };

    auto COMPUTE = [&](int bi) {
        const int xo = (quad ^ ((l16 >> 1) & 3)) * 8;
        const short* as = AS(bi);
        const short* bs = BS(bi);
        bf16x8 a[4], b[NT];
        #pragma unroll
        for (int mt = 0; mt < 4; ++mt)
            a[mt] = *(const bf16x8*)&as[(wr * 64 + mt * 16 + l16) * 32 + xo];
        #pragma unroll
        for (int nt = 0; nt < NT; ++nt)
            b[nt] = *(const bf16x8*)&bs[(wc * (TN / 2) + nt * 16 + l16) * 32 + xo];
        #pragma unroll
        for (int mt = 0; mt < 4; ++mt)
            #pragma unroll
            for (int nt = 0; nt < NT; ++nt)
                acc[mt][nt] = __builtin_amdgcn_mfma_f32_16x16x32_bf16(a[mt], b[nt], acc[mt][nt], 0, 0, 0);
    };

    const int nk = (K / GR) >> 5;
    // prologue: tiles 0,1 in flight (4 loads/lane each for TN=128)
    STAGE(0, 0);
    STAGE(1, 1);
    int bi = 0;
    for (int t = 0; t < nk - 1; ++t) {
        // counted wait: tile t's loads done; tile t+1's (youngest 4) may fly
        asm volatile("s_waitcnt vmcnt(4)" ::: "memory");
        __builtin_amdgcn_s_barrier();
        asm volatile("" ::: "memory");
        int bn = bi + 2 >= 3 ? bi - 1 : bi + 2;
        if (t + 2 < nk) STAGE(t + 2, bn);
        COMPUTE(bi);
        bi = bi + 1 >= 3 ? 0 : bi + 1;
    }
    asm volatile("s_waitcnt vmcnt(0)" ::: "memory");
    __builtin_amdgcn_s_barrier();
    asm volatile("" ::: "memory");
    COMPUTE(bi);

    if (GR == 2) {
        // cross-group reduction: group1 acc -> LDS (slice-major, conflict-free)
        float* red = (float*)smem;
        __syncthreads();   // staging LDS dead; safe to alias
        if (kgrp == 1) {
            #pragma unroll
            for (int mt = 0; mt < 4; ++mt)
                #pragma unroll
                for (int nt = 0; nt < NT; ++nt)
                    *(f32x4*)&red[((mt * NT + nt) * 256 + w4 * 64 + lane) * 4] = acc[mt][nt];
        }
        __syncthreads();
        if (kgrp == 1) return;
        #pragma unroll
        for (int mt = 0; mt < 4; ++mt)
            #pragma unroll
            for (int nt = 0; nt < NT; ++nt) {
                f32x4 p = *(const f32x4*)&red[((mt * NT + nt) * 256 + w4 * 64 + lane) * 4];
                acc[mt][nt] += p;
            }
    }

    const float qsc = (MODE == 5 && n0 < CD) ? 0.03125f * 1.44269504f : 1.0f;
    short* ob5 = (MODE == 5) ? outb + (size_t)(n0 >> 10) * BT * CD : nullptr;

    #pragma unroll
    for (int mt = 0; mt < 4; ++mt)
        #pragma unroll
        for (int nt = 0; nt < NT; ++nt)
            #pragma unroll
            for (int reg = 0; reg < 4; ++reg) {
                int row = m0 + wr * 64 + mt * 16 + quad * 4 + reg;
                int col = n0 + wc * (TN / 2) + nt * 16 + l16;
                float v = acc[mt][nt][reg];
                if (MODE == 1) { v += bias[col] + resid[(size_t)row * N + col];
                                 outf[(size_t)row * N + col] = v; }
                if (MODE == 2) { v = fmaxf(v + bias[col], 0.f);
                                 outb[(size_t)row * N + col] = f2bf(v); }
                if (MODE == 5) { ob5[(size_t)row * CD + (col & 1023)] = f2bf(v * qsc); }
            }
#undef AS
#undef BS
}

// ---------------- Flash attention, split-K, MFMA bf16, no-max softmax --------
// R14: K=32 PV via permuted-K storage. K rows are stored in LDS permuted
// within each 32-key span (storage row s of the even half holds key
// (s>>2)*8+(s&3); odd half +4). Two QK MFMAs per span (linear, conflict-free
// row reads) then give lane (quad,reg): even-acc keys quad*8+reg, odd-acc
// keys quad*8+4+reg -> exp2 + 4 cvt_pk concatenate into the EXACT K=32
// A-frag (k=quad*8+j). PV becomes mfma_16x16x32 with a single b128 V^T read
// per (dt,span): MFMA/tile 48 -> 32 (all K=32), V-reads 16xb64 -> 8xb128.
//  * 2-tile-deep register prefetch; counted vmcnt derived by compiler.
//  * STR 68: conflict-free for all access patterns; LDS 34816 B.
//  * setprio(1) around the MFMA/exp2 compute cluster; raw v_exp_f32.
#define BQ   128
#define BK   64
#define STR  68

__launch_bounds__(256)
__global__ void attn_mfma(const short* __restrict__ q,
                          const short* __restrict__ k,
                          const short* __restrict__ vt,
                          short* __restrict__ opart,
                          float* __restrict__ lpart) {
    __shared__ short Ks[2][BK * STR];
    __shared__ short Vt[2][DH * STR];

    const int tid  = threadIdx.x;
    const int w = tid >> 6, lane = tid & 63;
    const int quad = lane >> 4, l16 = lane & 15;
    const int h = blockIdx.y;
    const int b = blockIdx.z >> 1, split = blockIdx.z & 1;
    const int q0 = blockIdx.x * BQ;
    const size_t base  = (size_t)b * TD * CD + (size_t)h * DH;
    const size_t vbase = (size_t)(b * NH + h) * DH * TD;

    // Q frags (N-side of S^T mfma): lane holds Q[q=l16][d=quad*8+j]
    bf16x8 qf[2][2];
    #pragma unroll
    for (int rt = 0; rt < 2; ++rt) {
        const short* qp = q + base + (size_t)(q0 + w * 32 + rt * 16 + l16) * CD;
        qf[rt][0] = *(const bf16x8*)&qp[quad * 8];
        qf[rt][1] = *(const bf16x8*)&qp[32 + quad * 8];
    }

    float l_p[2] = {};   // per-lane partial l sums (key order irrelevant)
    f32x4 O[2][4] = {};

    const int kbeg = split * (TD / 2);
    const int NTI = (TD / 2) / BK;   // 16, even

    // per-lane staging coords: rows r8 / r8+32, cols c8..c8+7
    const int r8 = tid >> 3, c8 = (tid & 7) * 8;
    // sigma: key row -> permuted K storage row (within 32-key span)
    const int s32 = ((r8 & 4) << 2) + ((r8 >> 3) << 2) + (r8 & 3);
    const short* kg = k + base + c8;                       // + (kt+row)*CD
    const short* vg = vt + vbase + (size_t)r8 * TD + c8;   // + kt (+32*TD)

#define ISSUE_T(t, K0, K1, V0, V1) do {                                   \
        const size_t ko_ = (size_t)(kbeg + (t) * BK);                     \
        K0 = *(const bf16x8*)&kg[(ko_ + r8) * CD];                        \
        K1 = *(const bf16x8*)&kg[(ko_ + r8 + 32) * CD];                   \
        V0 = *(const bf16x8*)&vg[ko_];                                    \
        V1 = *(const bf16x8*)&vg[(size_t)32 * TD + ko_];                  \
    } while (0)

#define WRITE_T(buf, K0, K1, V0, V1) do {                                 \
        *(bf16x8*)&Ks[buf][s32 * STR + c8] = K0;                          \
        *(bf16x8*)&Ks[buf][(s32 + 32) * STR + c8] = K1;                   \
        *(bf16x8*)&Vt[buf][r8 * STR + c8] = V0;                           \
        *(bf16x8*)&Vt[buf][(r8 + 32) * STR + c8] = V1;                    \
    } while (0)

#define COMPUTE_T(buf) do {                                               \
        __builtin_amdgcn_s_setprio(1);                                    \
        _Pragma("unroll")                                                 \
        for (int sp = 0; sp < 2; ++sp) {                                  \
            bf16x8 kbe0 = *(const bf16x8*)&Ks[buf][(sp * 32 + l16) * STR + quad * 8];      \
            bf16x8 kbe1 = *(const bf16x8*)&Ks[buf][(sp * 32 + l16) * STR + 32 + quad * 8]; \
            bf16x8 kbo0 = *(const bf16x8*)&Ks[buf][(sp * 32 + 16 + l16) * STR + quad * 8]; \
            bf16x8 kbo1 = *(const bf16x8*)&Ks[buf][(sp * 32 + 16 + l16) * STR + 32 + quad * 8]; \
            bf16x8 pa8[2];                                                \
            _Pragma("unroll")                                             \
            for (int rt = 0; rt < 2; ++rt) {                              \
                f32x4 ae = (f32x4){0.f, 0.f, 0.f, 0.f};                   \
                f32x4 ao = (f32x4){0.f, 0.f, 0.f, 0.f};                   \
                ae = __builtin_amdgcn_mfma_f32_16x16x32_bf16(kbe0, qf[rt][0], ae, 0, 0, 0); \
                ae = __builtin_amdgcn_mfma_f32_16x16x32_bf16(kbe1, qf[rt][1], ae, 0, 0, 0); \
                ao = __builtin_amdgcn_mfma_f32_16x16x32_bf16(kbo0, qf[rt][0], ao, 0, 0, 0); \
                ao = __builtin_amdgcn_mfma_f32_16x16x32_bf16(kbo1, qf[rt][1], ao, 0, 0, 0); \
                float pe0 = EXP2(ae[0]), pe1 = EXP2(ae[1]);               \
                float pe2 = EXP2(ae[2]), pe3 = EXP2(ae[3]);               \
                float po0 = EXP2(ao[0]), po1 = EXP2(ao[1]);               \
                float po2 = EXP2(ao[2]), po3 = EXP2(ao[3]);               \
                l_p[rt] += ((pe0 + pe1) + (pe2 + pe3)) + ((po0 + po1) + (po2 + po3)); \
                union { u32x4 u; bf16x8 s; } cv_;                         \
                cv_.u = (u32x4){pk2bf(pe0, pe1), pk2bf(pe2, pe3),         \
                                pk2bf(po0, po1), pk2bf(po2, po3)};        \
                pa8[rt] = cv_.s;                                          \
            }                                                             \
            _Pragma("unroll")                                             \
            for (int dt = 0; dt < 4; ++dt) {                              \
                bf16x8 vb = *(const bf16x8*)&Vt[buf][(dt * 16 + l16) * STR + sp * 32 + quad * 8]; \
                O[0][dt] = __builtin_amdgcn_mfma_f32_16x16x32_bf16(pa8[0], vb, O[0][dt], 0, 0, 0); \
                O[1][dt] = __builtin_amdgcn_mfma_f32_16x16x32_bf16(pa8[1], vb, O[1][dt], 0, 0, 0); \
            }                                                             \
        }                                                                 \
        __builtin_amdgcn_s_setprio(0);                                    \
    } while (0)

    bf16x8 kA0, kA1, vA0, vA1;   // set A: odd tiles
    bf16x8 kB0, kB1, vB0, vB1;   // set B: even tiles

    // prologue: tile 0 direct to LDS[0] (one exposed latency), tile 1 -> A
    ISSUE_T(0, kA0, kA1, vA0, vA1);
    WRITE_T(0, kA0, kA1, vA0, vA1);
    ISSUE_T(1, kA0, kA1, vA0, vA1);
    __syncthreads();

    for (int it = 0; it < NTI; it += 2) {
        // tile it (LDS[0]); A holds tile it+1
        if (it + 2 < NTI) ISSUE_T(it + 2, kB0, kB1, vB0, vB1);
        COMPUTE_T(0);
        WRITE_T(1, kA0, kA1, vA0, vA1);
        __syncthreads();
        // tile it+1 (LDS[1]); B holds tile it+2
        if (it + 3 < NTI) ISSUE_T(it + 3, kA0, kA1, vA0, vA1);
        COMPUTE_T(1);
        if (it + 2 < NTI) WRITE_T(0, kB0, kB1, vB0, vB1);
        __syncthreads();
    }
#undef ISSUE_T
#undef WRITE_T
#undef COMPUTE_T

    // epilogue: unnormalized O (bf16) + l (fp32) per split
    short* osp = opart + (size_t)split * BT * CD;
    float* lsp = lpart + (size_t)split * BB * NH * TD + (size_t)(b * NH + h) * TD;
    #pragma unroll
    for (int rt = 0; rt < 2; ++rt) {
        float l = l_p[rt];
        l += __shfl_xor(l, 16, 64);
        l += __shfl_xor(l, 32, 64);
        if (lane < 16) lsp[q0 + w * 32 + rt * 16 + lane] = l;
        #pragma unroll
        for (int reg = 0; reg < 4; ++reg) {
            int row = q0 + w * 32 + rt * 16 + quad * 4 + reg;
            short* op = osp + base + (size_t)row * CD;
            #pragma unroll
            for (int dt = 0; dt < 4; ++dt)
                op[dt * 16 + l16] = f2bf(O[rt][dt][reg]);
        }
    }
}

// ---------------- Combine split-K partials: ob = (O0+O1)/(l0+l1), bf16 -------
__launch_bounds__(256)
__global__ void attn_combine(const short* __restrict__ opart,
                             const float* __restrict__ lpart,
                             short* __restrict__ ob) {
    const size_t idx = ((size_t)blockIdx.x * 256 + threadIdx.x) * 8;
    const int row = (int)(idx >> 10);        // / CD
    const int col = (int)(idx & 1023);
    const int b = row >> 11, qq = row & (TD - 1), hh = col >> 6;
    const size_t lbase = (size_t)(b * NH + hh) * TD + qq;
    const float l0 = lpart[lbase];
    const float l1 = lpart[(size_t)BB * NH * TD + lbase];
    const float inv = 1.f / (l0 + l1);
    bf16x8 a = *(const bf16x8*)&opart[idx];
    bf16x8 c = *(const bf16x8*)&opart[(size_t)BT * CD + idx];
    bf16x8 r;
    #pragma unroll
    for (int j = 0; j < 8; ++j)
        r[j] = f2bf((bf2f(a[j]) + bf2f(c[j])) * inv);
    *(bf16x8*)&ob[idx] = r;
}

extern "C" void kernel_launch(void* const* d_in, const int* in_sizes, int n_in,
                              void* d_out, int out_size, void* d_ws, size_t ws_size,
                              hipStream_t stream) {
    const float* x   = (const float*)d_in[0];
    const float* Wq  = (const float*)d_in[1];
    const float* Wk  = (const float*)d_in[2];
    const float* Wv  = (const float*)d_in[3];
    const float* Wo  = (const float*)d_in[4];
    const float* bo  = (const float*)d_in[5];
    const float* W1  = (const float*)d_in[6];
    const float* b1  = (const float*)d_in[7];
    const float* W2  = (const float*)d_in[8];
    const float* b2  = (const float*)d_in[9];
    const float* g1  = (const float*)d_in[10];
    const float* be1 = (const float*)d_in[11];
    const float* g2  = (const float*)d_in[12];
    const float* be2 = (const float*)d_in[13];
    float* out = (float*)d_out;

    const size_t SZ = (size_t)BT * CD;  // 4M elements
    float* ws  = (float*)d_ws;
    short* qbf = (short*)ws;                       // [0,1.5SZ): q|k|v bf16
    short* kbf = qbf + SZ;
    short* vbf = qbf + 2 * SZ;
    float* lpart = ws + SZ + SZ / 2;               // [1.5SZ,+128K floats)
    short* opart = (short*)(ws + 2 * SZ);          // [2SZ,3SZ): 2 x SZ bf16
    float* x1  = ws + 2 * SZ;                      // [2SZ,3SZ): after combine
    short* h   = (short*)(ws + 3 * SZ);            // [3SZ,3.5SZ)
    short* ob  = (short*)(ws + 3 * SZ + SZ / 2);   // [3.5SZ,4SZ)
    short* wqt = (short*)(ws + 4 * SZ);            // [4SZ,4.5SZ): 3xCD*CD + CD*CD
    short* wot = wqt + 3 * CD * CD;
    short* w1t = (short*)(ws + 4 * SZ + SZ / 2);   // [4.5SZ,5SZ)
    short* w2t = (short*)(ws + 5 * SZ);            // [5SZ,5.5SZ)
    short* vtg = (short*)(ws + 5 * SZ + SZ / 2);   // [5.5SZ,6SZ): V^T global
    short* ff1 = (short*)ws;                       // [0,2SZ): reuses dead q/k/v

    // 1) h1 = LN(x)  (bf16)
    ln_kernel<<<BT, 256, 0, stream>>>(x, g1, be1, h);

    // 2) all weight transposes fused (bf16 B^T layouts)
    prep_weights<<<3072, 256, 0, stream>>>(Wq, Wk, Wv, Wo, W1, W2, wqt, wot, w1t, w2t);

    // 3) merged q|k|v = h1 @ [Wq|Wk|Wv]  (bf16; C^-0.5*log2e folded into q)
    gemm_mfma<5, 128, 1><<<dim3(24, 32), 256, 0, stream>>>(h, wqt, nullptr, nullptr, nullptr, qbf, 3 * CD, CD);

    // 4) vtg = V^T per (b,h)
    vtrans<<<dim3(TD / 64, 2 * NH), 256, 0, stream>>>(vbf, vtg);

    // 5) attention split-K -> opart, lpart
    attn_mfma<<<dim3(TD / BQ, NH, BB * 2), 256, 0, stream>>>(qbf, kbf, vtg, opart, lpart);

    // 6) combine -> ob (bf16, concat-head layout)
    attn_combine<<<dim3((int)(SZ / (256 * 8))), 256, 0, stream>>>(opart, lpart, ob);

    // 7) x1 = ob @ Wo + bo + x  (fp32; 512-thr in-block split-K)
    gemm_mfma<1, 128, 2><<<dim3(8, 32), 512, 0, stream>>>(ob, wot, bo, x, x1, nullptr, CD, CD);

    // 8) h2 = LN(x1)  (bf16)
    ln_kernel<<<BT, 256, 0, stream>>>(x1, g2, be2, h);

    // 9) ff1 = relu(h2 @ W1 + b1)  (bf16, N=4096)
    gemm_mfma<2, 128, 1><<<dim3(32, 32), 256, 0, stream>>>(h, w1t, b1, nullptr, nullptr, ff1, 4 * CD, CD);

    // 10) out = ff1 @ W2 + b2 + x1  (fp32, K=4096, in-block split-K)
    gemm_mfma<1, 128, 2><<<dim3(8, 32), 512, 0, stream>>>(ff1, w2t, b2, x1, out, nullptr, CD, 4 * CD);
}

// Round 7
// 317.944 us; speedup vs baseline: 1.4109x; 1.0191x over previous
//
#include <hip/hip_runtime.h>
#include <hip/hip_bf16.h>

#define BT   4096   // B*T
#define CD   1024   // C
#define TD   2048   // T
#define NH   16     // heads
#define DH   64     // head dim
#define BB   2      // batch

typedef __attribute__((ext_vector_type(8))) short bf16x8;
typedef __attribute__((ext_vector_type(4))) short bf16x4;
typedef __attribute__((ext_vector_type(4))) float f32x4;
typedef __attribute__((ext_vector_type(2))) unsigned int u32x2;
typedef __attribute__((ext_vector_type(4))) unsigned int u32x4;

__device__ inline short f2bf(float f) {
    union { float fv; unsigned u; } x; x.fv = f;
    unsigned r = x.u + 0x7fffu + ((x.u >> 16) & 1u);
    return (short)(r >> 16);
}
__device__ inline float bf2f(short s) {
    union { unsigned u; float f; } x; x.u = ((unsigned)(unsigned short)s) << 16;
    return x.f;
}
__device__ inline unsigned pk2bf(float a, float b) {
    union { __hip_bfloat162 h; unsigned u; } cv;
    cv.h = __float22bfloat162_rn(float2{a, b});
    return cv.u;
}

// raw v_exp_f32 (2^x): avoid any OCML guard sequence
#if __has_builtin(__builtin_amdgcn_exp2f)
#define EXP2(x) __builtin_amdgcn_exp2f(x)
#else
#define EXP2(x) exp2f(x)
#endif

__device__ inline void gload_lds16(const short* g, short* lds) {
    __builtin_amdgcn_global_load_lds(
        (const __attribute__((address_space(1))) void*)g,
        (__attribute__((address_space(3))) void*)lds, 16, 0, 0);
}

// ---------------- LayerNorm: one block per row (C=1024), fp32 in, bf16 out ----
// R15: float4 loads (one per thread), row kept in regs for the normalize pass
// (no second x read), short4 output store.
__launch_bounds__(256)
__global__ void ln_kernel(const float* __restrict__ x,
                          const float* __restrict__ g,
                          const float* __restrict__ be,
                          short* __restrict__ out) {
    __shared__ float red[2][4];
    const int row = blockIdx.x;
    const int c4 = threadIdx.x * 4;
    const float* xr = x + (size_t)row * CD;
    float4 v = *(const float4*)&xr[c4];
    float s  = (v.x + v.y) + (v.z + v.w);
    float ss = (v.x * v.x + v.y * v.y) + (v.z * v.z + v.w * v.w);
    #pragma unroll
    for (int off = 32; off > 0; off >>= 1) {
        s  += __shfl_down(s,  off, 64);
        ss += __shfl_down(ss, off, 64);
    }
    int wid = threadIdx.x >> 6, lane = threadIdx.x & 63;
    if (lane == 0) { red[0][wid] = s; red[1][wid] = ss; }
    __syncthreads();
    float sum   = red[0][0] + red[0][1] + red[0][2] + red[0][3];
    float sumsq = red[1][0] + red[1][1] + red[1][2] + red[1][3];
    float mu   = sum * (1.f / CD);
    float var  = sumsq * (1.f / CD) - mu * mu;
    float rstd = rsqrtf(var + 1e-5f);
    float4 gv = *(const float4*)&g[c4];
    float4 bv = *(const float4*)&be[c4];
    bf16x4 o;
    o[0] = f2bf((v.x - mu) * rstd * gv.x + bv.x);
    o[1] = f2bf((v.y - mu) * rstd * gv.y + bv.y);
    o[2] = f2bf((v.z - mu) * rstd * gv.z + bv.z);
    o[3] = f2bf((v.w - mu) * rstd * gv.w + bv.w);
    *(bf16x4*)&out[(size_t)row * CD + c4] = o;
}

// ------------- Fused weight prep: all 64x64 fp32->bf16 transpose tiles -------
// blocks 0..767: Wq/Wk/Wv (per-head CDxDH slices) -> wqt (3,H,DH,C)
// 768..1023: Wo (CDxCD); 1024..2047: W1 (CDx4CD); 2048..3071: W2 (4CDxCD)
// R15: float4 input loads (16B/lane); LDS stores stay scalar (65-pad align).
__launch_bounds__(256)
__global__ void prep_weights(const float* __restrict__ Wq, const float* __restrict__ Wk,
                             const float* __restrict__ Wv, const float* __restrict__ Wo,
                             const float* __restrict__ W1, const float* __restrict__ W2,
                             short* __restrict__ wqt, short* __restrict__ wot,
                             short* __restrict__ w1t, short* __restrict__ w2t) {
    __shared__ float tt[64][65];
    const int id = blockIdx.x;
    const float* in; short* out; int R, Cc, r0, c0;
    if (id < 768) {
        int which = id >> 8, rem = id & 255, hh = rem >> 4, ry = rem & 15;
        in  = (which == 0 ? Wq : which == 1 ? Wk : Wv) + (size_t)hh * CD * DH;
        out = wqt + (size_t)which * CD * CD + (size_t)hh * DH * CD;
        R = CD; Cc = DH; r0 = ry * 64; c0 = 0;
    } else if (id < 1024) {
        int t = id - 768;  in = Wo; out = wot; R = CD;     Cc = CD;     r0 = (t >> 4) * 64; c0 = (t & 15) * 64;
    } else if (id < 2048) {
        int t = id - 1024; in = W1; out = w1t; R = CD;     Cc = 4 * CD; r0 = (t >> 6) * 64; c0 = (t & 63) * 64;
    } else {
        int t = id - 2048; in = W2; out = w2t; R = 4 * CD; Cc = CD;     r0 = (t >> 4) * 64; c0 = (t & 15) * 64;
    }
    const int tid = threadIdx.x;
    #pragma unroll
    for (int i = 0; i < 4; ++i) {
        int f = i * 256 + tid;             // float4 index within 64x64 tile
        int r = f >> 4, cc = (f & 15) * 4;
        float4 vv = *(const float4*)&in[(size_t)(r0 + r) * Cc + c0 + cc];
        tt[r][cc]     = vv.x;
        tt[r][cc + 1] = vv.y;
        tt[r][cc + 2] = vv.z;
        tt[r][cc + 3] = vv.w;
    }
    __syncthreads();
    #pragma unroll
    for (int i = 0; i < 16; ++i) {
        int e = i * 256 + tid;
        out[(size_t)(c0 + (e >> 6)) * R + r0 + (e & 63)] = f2bf(tt[e & 63][e >> 6]);
    }
}

// ------------- V transpose: vbf (BT x C bf16) -> vtg[b][h][d][t] bf16 -------
__launch_bounds__(256)
__global__ void vtrans(const short* __restrict__ vin, short* __restrict__ vout) {
    __shared__ short t[64 * 65];
    const int tid = threadIdx.x;
    const int bh = blockIdx.y;
    const int t0 = blockIdx.x * 64;
    const int b = bh >> 4, h = bh & 15;
    const short* src = vin + (size_t)b * TD * CD + (size_t)h * DH;
    short* dst = vout + (size_t)bh * DH * TD;
    #pragma unroll
    for (int i = 0; i < 16; ++i) {
        int e = i * 256 + tid;
        t[(e >> 6) * 65 + (e & 63)] = src[(size_t)(t0 + (e >> 6)) * CD + (e & 63)];
    }
    __syncthreads();
    #pragma unroll
    for (int i = 0; i < 16; ++i) {
        int e = i * 256 + tid;
        int d = e >> 6, tt = e & 63;
        dst[(size_t)d * TD + t0 + tt] = t[tt * 65 + d];
    }
}

// ---------------- MFMA GEMM: C(128 x TN) = A(M x K) . Bt(N x K)^T, bf16 ------
// Triple-buffered LDS + counted vmcnt(4) + raw barriers; XOR-swizzled 16B
// slots -> conflict-free ds_read_b128 with linear gload_lds dest.
// GR=2 (512 threads): in-block split-K (two 4-wave groups, private LDS
// triple-buffers, lockstep barriers; group1 reduces via LDS at the end).
// XCD-aware tile swizzle: XCD k = li&7 owns m-tiles [4k,4k+4) x all n-tiles
// -> A-row-panel is L2-local per XCD instead of an 8-32x LLC/HBM re-read.
// MODE 1: + bias + fp32 resid -> fp32 out
// MODE 2: + bias, relu -> bf16 out
// MODE 5: QKV merged: N=3072; seg=col>>10 -> outb + seg*BT*CD; seg0 scaled by
//         C^-0.5 * log2(e)  (attention uses exp2)
template <int MODE, int TN, int GR>
__launch_bounds__(GR * 256)
__global__ void gemm_mfma(const short* __restrict__ A,
                          const short* __restrict__ Bt,
                          const float* __restrict__ bias,
                          const float* __restrict__ resid,
                          float* __restrict__ outf,
                          short* __restrict__ outb,
                          int N, int K) {
    // per group: 3 buffers of (128 + TN) rows x 32 cols bf16
    __shared__ __align__(16) short smem[GR * 3 * (128 + TN) * 32];
    const int tid = threadIdx.x;
    const int kgrp = (GR == 2) ? (tid >> 8) : 0;
    const int tid256 = tid & 255;
    const int w4 = tid256 >> 6, lane = tid & 63;
    const int quad = lane >> 4, l16 = lane & 15;
    const int wr = w4 >> 1, wc = w4 & 1;
    // XCD-aware swizzle: li -> (m-tile, n-tile); XCD k = li&7 owns m 4k..4k+4
    const int li = blockIdx.y * gridDim.x + blockIdx.x;
    const int m0 = ((li & 7) * 4 + ((li >> 3) & 3)) * 128;
    const int n0 = (li >> 5) * TN;
    const int NT = TN / 32;
    const int kbase = kgrp * (K / GR);

    short* grpBase = smem + (size_t)kgrp * 3 * (128 + TN) * 32;
#define AS(bi) (grpBase + (bi) * (128 + TN) * 32)
#define BS(bi) (AS(bi) + 128 * 32)

    f32x4 acc[4][NT] = {};

    auto STAGE = [&](int kt, int bi) {
        const int k0 = kbase + kt * 32;
        short* as = AS(bi);
        short* bs = BS(bi);
        #pragma unroll
        for (int i = 0; i < 2; ++i) {
            int s = i * 256 + tid256;
            int row = s >> 2, kc = (s & 3) ^ ((row >> 1) & 3);
            gload_lds16(A + (size_t)(m0 + row) * K + k0 + kc * 8,
                        &as[(i * 256 + w4 * 64) * 8]);
        }
        #pragma unroll
        for (int i = 0; i < TN / 64; ++i) {
            int s = i * 256 + tid256;
            int row = s >> 2, kc = (s & 3) ^ ((row >> 1) & 3);
            gload_lds16(Bt + (size_t)(n0 + row) * K + k0 + kc * 8,
                        &bs[(i * 256 + w4 * 64) * 8]);
        }
    };

    auto COMPUTE = [&](int bi) {
        const int xo = (quad ^ ((l16 >> 1) & 3)) * 8;
        const short* as = AS(bi);
        const short* bs = BS(bi);
        bf16x8 a[4], b[NT];
        #pragma unroll
        for (int mt = 0; mt < 4; ++mt)
            a[mt] = *(const bf16x8*)&as[(wr * 64 + mt * 16 + l16) * 32 + xo];
        #pragma unroll
        for (int nt = 0; nt < NT; ++nt)
            b[nt] = *(const bf16x8*)&bs[(wc * (TN / 2) + nt * 16 + l16) * 32 + xo];
        #pragma unroll
        for (int mt = 0; mt < 4; ++mt)
            #pragma unroll
            for (int nt = 0; nt < NT; ++nt)
                acc[mt][nt] = __builtin_amdgcn_mfma_f32_16x16x32_bf16(a[mt], b[nt], acc[mt][nt], 0, 0, 0);
    };

    const int nk = (K / GR) >> 5;
    // prologue: tiles 0,1 in flight (4 loads/lane each for TN=128)
    STAGE(0, 0);
    STAGE(1, 1);
    int bi = 0;
    for (int t = 0; t < nk - 1; ++t) {
        // counted wait: tile t's loads done; tile t+1's (youngest 4) may fly
        asm volatile("s_waitcnt vmcnt(4)" ::: "memory");
        __builtin_amdgcn_s_barrier();
        asm volatile("" ::: "memory");
        int bn = bi + 2 >= 3 ? bi - 1 : bi + 2;
        if (t + 2 < nk) STAGE(t + 2, bn);
        COMPUTE(bi);
        bi = bi + 1 >= 3 ? 0 : bi + 1;
    }
    asm volatile("s_waitcnt vmcnt(0)" ::: "memory");
    __builtin_amdgcn_s_barrier();
    asm volatile("" ::: "memory");
    COMPUTE(bi);

    if (GR == 2) {
        // cross-group reduction: group1 acc -> LDS (slice-major, conflict-free)
        float* red = (float*)smem;
        __syncthreads();   // staging LDS dead; safe to alias
        if (kgrp == 1) {
            #pragma unroll
            for (int mt = 0; mt < 4; ++mt)
                #pragma unroll
                for (int nt = 0; nt < NT; ++nt)
                    *(f32x4*)&red[((mt * NT + nt) * 256 + w4 * 64 + lane) * 4] = acc[mt][nt];
        }
        __syncthreads();
        if (kgrp == 1) return;
        #pragma unroll
        for (int mt = 0; mt < 4; ++mt)
            #pragma unroll
            for (int nt = 0; nt < NT; ++nt) {
                f32x4 p = *(const f32x4*)&red[((mt * NT + nt) * 256 + w4 * 64 + lane) * 4];
                acc[mt][nt] += p;
            }
    }

    const float qsc = (MODE == 5 && n0 < CD) ? 0.03125f * 1.44269504f : 1.0f;
    short* ob5 = (MODE == 5) ? outb + (size_t)(n0 >> 10) * BT * CD : nullptr;

    #pragma unroll
    for (int mt = 0; mt < 4; ++mt)
        #pragma unroll
        for (int nt = 0; nt < NT; ++nt)
            #pragma unroll
            for (int reg = 0; reg < 4; ++reg) {
                int row = m0 + wr * 64 + mt * 16 + quad * 4 + reg;
                int col = n0 + wc * (TN / 2) + nt * 16 + l16;
                float v = acc[mt][nt][reg];
                if (MODE == 1) { v += bias[col] + resid[(size_t)row * N + col];
                                 outf[(size_t)row * N + col] = v; }
                if (MODE == 2) { v = fmaxf(v + bias[col], 0.f);
                                 outb[(size_t)row * N + col] = f2bf(v); }
                if (MODE == 5) { ob5[(size_t)row * CD + (col & 1023)] = f2bf(v * qsc); }
            }
#undef AS
#undef BS
}

// ---------------- Flash attention, split-K, MFMA bf16, no-max softmax --------
// K=32 PV via permuted-K storage (R14). R15: l-sum via MFMA ones-column:
// O_l[rt] = mfma(pa8[rt], ones8, O_l[rt]) -> l[q=quad*4+reg] = O_l[rt][reg].
// Removes all 32 VALU l-adds/tile + epilogue shfl_xor; l is the sum of the
// bf16-rounded P actually used in PV (the consistent denominator). The 4
// extra MFMA/tile ride the ~73%-idle MFMA pipe.
//  * 2-tile-deep register prefetch; counted vmcnt derived by compiler.
//  * STR 68: conflict-free for all access patterns; LDS 34816 B.
//  * setprio(1) around the MFMA/exp2 compute cluster; raw v_exp_f32.
#define BQ   128
#define BK   64
#define STR  68

__launch_bounds__(256)
__global__ void attn_mfma(const short* __restrict__ q,
                          const short* __restrict__ k,
                          const short* __restrict__ vt,
                          short* __restrict__ opart,
                          float* __restrict__ lpart) {
    __shared__ short Ks[2][BK * STR];
    __shared__ short Vt[2][DH * STR];

    const int tid  = threadIdx.x;
    const int w = tid >> 6, lane = tid & 63;
    const int quad = lane >> 4, l16 = lane & 15;
    const int h = blockIdx.y;
    const int b = blockIdx.z >> 1, split = blockIdx.z & 1;
    const int q0 = blockIdx.x * BQ;
    const size_t base  = (size_t)b * TD * CD + (size_t)h * DH;
    const size_t vbase = (size_t)(b * NH + h) * DH * TD;

    // Q frags (N-side of S^T mfma): lane holds Q[q=l16][d=quad*8+j]
    bf16x8 qf[2][2];
    #pragma unroll
    for (int rt = 0; rt < 2; ++rt) {
        const short* qp = q + base + (size_t)(q0 + w * 32 + rt * 16 + l16) * CD;
        qf[rt][0] = *(const bf16x8*)&qp[quad * 8];
        qf[rt][1] = *(const bf16x8*)&qp[32 + quad * 8];
    }

    const bf16x8 ones = {(short)0x3F80, (short)0x3F80, (short)0x3F80, (short)0x3F80,
                         (short)0x3F80, (short)0x3F80, (short)0x3F80, (short)0x3F80};
    f32x4 O_l[2] = {};   // l accumulator: row q=quad*4+reg (col replicated)
    f32x4 O[2][4] = {};

    const int kbeg = split * (TD / 2);
    const int NTI = (TD / 2) / BK;   // 16, even

    // per-lane staging coords: rows r8 / r8+32, cols c8..c8+7
    const int r8 = tid >> 3, c8 = (tid & 7) * 8;
    // sigma: key row -> permuted K storage row (within 32-key span)
    const int s32 = ((r8 & 4) << 2) + ((r8 >> 3) << 2) + (r8 & 3);
    const short* kg = k + base + c8;                       // + (kt+row)*CD
    const short* vg = vt + vbase + (size_t)r8 * TD + c8;   // + kt (+32*TD)

#define ISSUE_T(t, K0, K1, V0, V1) do {                                   \
        const size_t ko_ = (size_t)(kbeg + (t) * BK);                     \
        K0 = *(const bf16x8*)&kg[(ko_ + r8) * CD];                        \
        K1 = *(const bf16x8*)&kg[(ko_ + r8 + 32) * CD];                   \
        V0 = *(const bf16x8*)&vg[ko_];                                    \
        V1 = *(const bf16x8*)&vg[(size_t)32 * TD + ko_];                  \
    } while (0)

#define WRITE_T(buf, K0, K1, V0, V1) do {                                 \
        *(bf16x8*)&Ks[buf][s32 * STR + c8] = K0;                          \
        *(bf16x8*)&Ks[buf][(s32 + 32) * STR + c8] = K1;                   \
        *(bf16x8*)&Vt[buf][r8 * STR + c8] = V0;                           \
        *(bf16x8*)&Vt[buf][(r8 + 32) * STR + c8] = V1;                    \
    } while (0)

#define COMPUTE_T(buf) do {                                               \
        __builtin_amdgcn_s_setprio(1);                                    \
        _Pragma("unroll")                                                 \
        for (int sp = 0; sp < 2; ++sp) {                                  \
            bf16x8 kbe0 = *(const bf16x8*)&Ks[buf][(sp * 32 + l16) * STR + quad * 8];      \
            bf16x8 kbe1 = *(const bf16x8*)&Ks[buf][(sp * 32 + l16) * STR + 32 + quad * 8]; \
            bf16x8 kbo0 = *(const bf16x8*)&Ks[buf][(sp * 32 + 16 + l16) * STR + quad * 8]; \
            bf16x8 kbo1 = *(const bf16x8*)&Ks[buf][(sp * 32 + 16 + l16) * STR + 32 + quad * 8]; \
            bf16x8 pa8[2];                                                \
            _Pragma("unroll")                                             \
            for (int rt = 0; rt < 2; ++rt) {                              \
                f32x4 ae = (f32x4){0.f, 0.f, 0.f, 0.f};                   \
                f32x4 ao = (f32x4){0.f, 0.f, 0.f, 0.f};                   \
                ae = __builtin_amdgcn_mfma_f32_16x16x32_bf16(kbe0, qf[rt][0], ae, 0, 0, 0); \
                ae = __builtin_amdgcn_mfma_f32_16x16x32_bf16(kbe1, qf[rt][1], ae, 0, 0, 0); \
                ao = __builtin_amdgcn_mfma_f32_16x16x32_bf16(kbo0, qf[rt][0], ao, 0, 0, 0); \
                ao = __builtin_amdgcn_mfma_f32_16x16x32_bf16(kbo1, qf[rt][1], ao, 0, 0, 0); \
                float pe0 = EXP2(ae[0]), pe1 = EXP2(ae[1]);               \
                float pe2 = EXP2(ae[2]), pe3 = EXP2(ae[3]);               \
                float po0 = EXP2(ao[0]), po1 = EXP2(ao[1]);               \
                float po2 = EXP2(ao[2]), po3 = EXP2(ao[3]);               \
                union { u32x4 u; bf16x8 s; } cv_;                         \
                cv_.u = (u32x4){pk2bf(pe0, pe1), pk2bf(pe2, pe3),         \
                                pk2bf(po0, po1), pk2bf(po2, po3)};        \
                pa8[rt] = cv_.s;                                          \
            }                                                             \
            _Pragma("unroll")                                             \
            for (int dt = 0; dt < 4; ++dt) {                              \
                bf16x8 vb = *(const bf16x8*)&Vt[buf][(dt * 16 + l16) * STR + sp * 32 + quad * 8]; \
                O[0][dt] = __builtin_amdgcn_mfma_f32_16x16x32_bf16(pa8[0], vb, O[0][dt], 0, 0, 0); \
                O[1][dt] = __builtin_amdgcn_mfma_f32_16x16x32_bf16(pa8[1], vb, O[1][dt], 0, 0, 0); \
            }                                                             \
            O_l[0] = __builtin_amdgcn_mfma_f32_16x16x32_bf16(pa8[0], ones, O_l[0], 0, 0, 0); \
            O_l[1] = __builtin_amdgcn_mfma_f32_16x16x32_bf16(pa8[1], ones, O_l[1], 0, 0, 0); \
        }                                                                 \
        __builtin_amdgcn_s_setprio(0);                                    \
    } while (0)

    bf16x8 kA0, kA1, vA0, vA1;   // set A: odd tiles
    bf16x8 kB0, kB1, vB0, vB1;   // set B: even tiles

    // prologue: tile 0 direct to LDS[0] (one exposed latency), tile 1 -> A
    ISSUE_T(0, kA0, kA1, vA0, vA1);
    WRITE_T(0, kA0, kA1, vA0, vA1);
    ISSUE_T(1, kA0, kA1, vA0, vA1);
    __syncthreads();

    for (int it = 0; it < NTI; it += 2) {
        // tile it (LDS[0]); A holds tile it+1
        if (it + 2 < NTI) ISSUE_T(it + 2, kB0, kB1, vB0, vB1);
        COMPUTE_T(0);
        WRITE_T(1, kA0, kA1, vA0, vA1);
        __syncthreads();
        // tile it+1 (LDS[1]); B holds tile it+2
        if (it + 3 < NTI) ISSUE_T(it + 3, kA0, kA1, vA0, vA1);
        COMPUTE_T(1);
        if (it + 2 < NTI) WRITE_T(0, kB0, kB1, vB0, vB1);
        __syncthreads();
    }
#undef ISSUE_T
#undef WRITE_T
#undef COMPUTE_T

    // epilogue: unnormalized O (bf16) + l (fp32) per split
    short* osp = opart + (size_t)split * BT * CD;
    float* lsp = lpart + (size_t)split * BB * NH * TD + (size_t)(b * NH + h) * TD;
    #pragma unroll
    for (int rt = 0; rt < 2; ++rt) {
        if (l16 == 0)
            *(f32x4*)&lsp[q0 + w * 32 + rt * 16 + quad * 4] = O_l[rt];
        #pragma unroll
        for (int reg = 0; reg < 4; ++reg) {
            int row = q0 + w * 32 + rt * 16 + quad * 4 + reg;
            short* op = osp + base + (size_t)row * CD;
            #pragma unroll
            for (int dt = 0; dt < 4; ++dt)
                op[dt * 16 + l16] = f2bf(O[rt][dt][reg]);
        }
    }
}

// ---------------- Combine split-K partials: ob = (O0+O1)/(l0+l1), bf16 -------
__launch_bounds__(256)
__global__ void attn_combine(const short* __restrict__ opart,
                             const float* __restrict__ lpart,
                             short* __restrict__ ob) {
    const size_t idx = ((size_t)blockIdx.x * 256 + threadIdx.x) * 8;
    const int row = (int)(idx >> 10);        // / CD
    const int col = (int)(idx & 1023);
    const int b = row >> 11, qq = row & (TD - 1), hh = col >> 6;
    const size_t lbase = (size_t)(b * NH + hh) * TD + qq;
    const float l0 = lpart[lbase];
    const float l1 = lpart[(size_t)BB * NH * TD + lbase];
    const float inv = 1.f / (l0 + l1);
    bf16x8 a = *(const bf16x8*)&opart[idx];
    bf16x8 c = *(const bf16x8*)&opart[(size_t)BT * CD + idx];
    bf16x8 r;
    #pragma unroll
    for (int j = 0; j < 8; ++j)
        r[j] = f2bf((bf2f(a[j]) + bf2f(c[j])) * inv);
    *(bf16x8*)&ob[idx] = r;
}

extern "C" void kernel_launch(void* const* d_in, const int* in_sizes, int n_in,
                              void* d_out, int out_size, void* d_ws, size_t ws_size,
                              hipStream_t stream) {
    const float* x   = (const float*)d_in[0];
    const float* Wq  = (const float*)d_in[1];
    const float* Wk  = (const float*)d_in[2];
    const float* Wv  = (const float*)d_in[3];
    const float* Wo  = (const float*)d_in[4];
    const float* bo  = (const float*)d_in[5];
    const float* W1  = (const float*)d_in[6];
    const float* b1  = (const float*)d_in[7];
    const float* W2  = (const float*)d_in[8];
    const float* b2  = (const float*)d_in[9];
    const float* g1  = (const float*)d_in[10];
    const float* be1 = (const float*)d_in[11];
    const float* g2  = (const float*)d_in[12];
    const float* be2 = (const float*)d_in[13];
    float* out = (float*)d_out;

    const size_t SZ = (size_t)BT * CD;  // 4M elements
    float* ws  = (float*)d_ws;
    short* qbf = (short*)ws;                       // [0,1.5SZ): q|k|v bf16
    short* kbf = qbf + SZ;
    short* vbf = qbf + 2 * SZ;
    float* lpart = ws + SZ + SZ / 2;               // [1.5SZ,+128K floats)
    short* opart = (short*)(ws + 2 * SZ);          // [2SZ,3SZ): 2 x SZ bf16
    float* x1  = ws + 2 * SZ;                      // [2SZ,3SZ): after combine
    short* h   = (short*)(ws + 3 * SZ);            // [3SZ,3.5SZ)
    short* ob  = (short*)(ws + 3 * SZ + SZ / 2);   // [3.5SZ,4SZ)
    short* wqt = (short*)(ws + 4 * SZ);            // [4SZ,4.5SZ): 3xCD*CD + CD*CD
    short* wot = wqt + 3 * CD * CD;
    short* w1t = (short*)(ws + 4 * SZ + SZ / 2);   // [4.5SZ,5SZ)
    short* w2t = (short*)(ws + 5 * SZ);            // [5SZ,5.5SZ)
    short* vtg = (short*)(ws + 5 * SZ + SZ / 2);   // [5.5SZ,6SZ): V^T global
    short* ff1 = (short*)ws;                       // [0,2SZ): reuses dead q/k/v

    // 1) h1 = LN(x)  (bf16)
    ln_kernel<<<BT, 256, 0, stream>>>(x, g1, be1, h);

    // 2) all weight transposes fused (bf16 B^T layouts)
    prep_weights<<<3072, 256, 0, stream>>>(Wq, Wk, Wv, Wo, W1, W2, wqt, wot, w1t, w2t);

    // 3) merged q|k|v = h1 @ [Wq|Wk|Wv]  (bf16; C^-0.5*log2e folded into q)
    gemm_mfma<5, 128, 1><<<dim3(24, 32), 256, 0, stream>>>(h, wqt, nullptr, nullptr, nullptr, qbf, 3 * CD, CD);

    // 4) vtg = V^T per (b,h)
    vtrans<<<dim3(TD / 64, 2 * NH), 256, 0, stream>>>(vbf, vtg);

    // 5) attention split-K -> opart, lpart
    attn_mfma<<<dim3(TD / BQ, NH, BB * 2), 256, 0, stream>>>(qbf, kbf, vtg, opart, lpart);

    // 6) combine -> ob (bf16, concat-head layout)
    attn_combine<<<dim3((int)(SZ / (256 * 8))), 256, 0, stream>>>(opart, lpart, ob);

    // 7) x1 = ob @ Wo + bo + x  (fp32; 512-thr in-block split-K)
    gemm_mfma<1, 128, 2><<<dim3(8, 32), 512, 0, stream>>>(ob, wot, bo, x, x1, nullptr, CD, CD);

    // 8) h2 = LN(x1)  (bf16)
    ln_kernel<<<BT, 256, 0, stream>>>(x1, g2, be2, h);

    // 9) ff1 = relu(h2 @ W1 + b1)  (bf16, N=4096)
    gemm_mfma<2, 128, 1><<<dim3(32, 32), 256, 0, stream>>>(h, w1t, b1, nullptr, nullptr, ff1, 4 * CD, CD);

    // 10) out = ff1 @ W2 + b2 + x1  (fp32, K=4096, in-block split-K)
    gemm_mfma<1, 128, 2><<<dim3(8, 32), 512, 0, stream>>>(ff1, w2t, b2, x1, out, nullptr, CD, 4 * CD);
}